// Round 1
// baseline (1882.985 us; speedup 1.0000x reference)
//
#include <hip/hip_runtime.h>
#include <math.h>

#define BATCH 2
#define SEQ   2048
#define DM    1024
#define DI    2048
#define NST   16
#define DR    64
#define MT    (BATCH*SEQ)   // 4096

// ---------------------------------------------------------------------------
// SGEMM: C(M,N) = A(M,K,lda) @ B(N,K,ldb)^T + bias(N)
// 128x128 tile, BK=8, 256 threads, 8x8 micro-tile per thread.
// grid = (N/128, M/128)
// ---------------------------------------------------------------------------
__global__ __launch_bounds__(256) void sgemm_abT(
    const float* __restrict__ A, int lda,
    const float* __restrict__ B, int ldb,
    const float* __restrict__ bias,
    float* __restrict__ C, int ldc, int K)
{
  __shared__ float As[8][128];
  __shared__ float Bs[8][128];
  const int tid = threadIdx.x;
  const int tx = tid & 15, ty = tid >> 4;
  const int bx = blockIdx.x, by = blockIdx.y;
  const int arow = tid >> 1;          // 0..127
  const int acol = (tid & 1) * 4;     // 0 or 4
  const float* Ap = A + (size_t)(by*128 + arow)*lda + acol;
  const float* Bp = B + (size_t)(bx*128 + arow)*ldb + acol;

  float acc[8][8];
#pragma unroll
  for (int i = 0; i < 8; ++i)
#pragma unroll
    for (int j = 0; j < 8; ++j) acc[i][j] = 0.f;

  for (int k0 = 0; k0 < K; k0 += 8) {
    float4 av = *(const float4*)(Ap + k0);
    float4 bv = *(const float4*)(Bp + k0);
    __syncthreads();   // protect previous iteration's LDS reads
    As[acol+0][arow] = av.x; As[acol+1][arow] = av.y;
    As[acol+2][arow] = av.z; As[acol+3][arow] = av.w;
    Bs[acol+0][arow] = bv.x; Bs[acol+1][arow] = bv.y;
    Bs[acol+2][arow] = bv.z; Bs[acol+3][arow] = bv.w;
    __syncthreads();
#pragma unroll
    for (int k = 0; k < 8; ++k) {
      float4 a0 = *(const float4*)&As[k][ty*8];
      float4 a1 = *(const float4*)&As[k][ty*8+4];
      float4 b0 = *(const float4*)&Bs[k][tx*4];
      float4 b1 = *(const float4*)&Bs[k][tx*4+64];
      float fa[8] = {a0.x,a0.y,a0.z,a0.w,a1.x,a1.y,a1.z,a1.w};
      float fb[8] = {b0.x,b0.y,b0.z,b0.w,b1.x,b1.y,b1.z,b1.w};
#pragma unroll
      for (int i = 0; i < 8; ++i)
#pragma unroll
        for (int j = 0; j < 8; ++j)
          acc[i][j] += fa[i]*fb[j];
    }
  }

  const int n0 = bx*128 + tx*4;
  float4 bias0 = *(const float4*)(bias + n0);
  float4 bias1 = *(const float4*)(bias + n0 + 64);
#pragma unroll
  for (int i = 0; i < 8; ++i) {
    int row = by*128 + ty*8 + i;
    float4 c0 = {acc[i][0]+bias0.x, acc[i][1]+bias0.y,
                 acc[i][2]+bias0.z, acc[i][3]+bias0.w};
    float4 c1 = {acc[i][4]+bias1.x, acc[i][5]+bias1.y,
                 acc[i][6]+bias1.z, acc[i][7]+bias1.w};
    *(float4*)(C + (size_t)row*ldc + n0)      = c0;
    *(float4*)(C + (size_t)row*ldc + n0 + 64) = c1;
  }
}

// ---------------------------------------------------------------------------
// dbc(m, 0..95) = x_row(m) . W_x[n] + b_x[n];  x = ui[:, 0:2048]
// block = 128 threads, handles 8 rows of m; x rows staged in LDS.
// grid = MT/8 = 512
// ---------------------------------------------------------------------------
__global__ __launch_bounds__(128) void dbc_kernel(
    const float* __restrict__ ui, const float* __restrict__ Wx,
    const float* __restrict__ bx, float* __restrict__ dbc)
{
  __shared__ float xrow[8][2048];   // 64 KiB
  const int m0 = blockIdx.x * 8;
  for (int i = threadIdx.x; i < 8*512; i += 128) {
    int r = i >> 9, c4 = i & 511;
    *(float4*)&xrow[r][c4*4] = *(const float4*)(ui + (size_t)(m0+r)*4096 + c4*4);
  }
  __syncthreads();
  const int n = threadIdx.x;
  if (n < 96) {
    const float* w = Wx + (size_t)n*2048;
    float s[8];
#pragma unroll
    for (int r = 0; r < 8; ++r) s[r] = 0.f;
    for (int k = 0; k < 2048; k += 4) {
      float4 wv = *(const float4*)(w + k);
#pragma unroll
      for (int r = 0; r < 8; ++r) {
        s[r] += xrow[r][k]*wv.x + xrow[r][k+1]*wv.y
              + xrow[r][k+2]*wv.z + xrow[r][k+3]*wv.w;
      }
    }
    float bb = bx[n];
#pragma unroll
    for (int r = 0; r < 8; ++r)
      dbc[(size_t)(m0+r)*96 + n] = s[r] + bb;
  }
}

// ---------------------------------------------------------------------------
// delta(m,n) = softplus( dbc[m, 0:64] . W_dt[n] + b_dt[n] )
// block = 256 threads (one n each), 16 m-rows staged in LDS, W_dt row in regs.
// grid = (DI/256, MT/16) = (8, 256)
// ---------------------------------------------------------------------------
__global__ __launch_bounds__(256) void delta_kernel(
    const float* __restrict__ dbc, const float* __restrict__ Wdt,
    const float* __restrict__ bdt, float* __restrict__ delta)
{
  __shared__ float draw[16][64];
  const int n  = blockIdx.x * 256 + threadIdx.x;
  const int m0 = blockIdx.y * 16;
  {
    int t = threadIdx.x;           // 256 float4 = 16 rows x 16 float4
    int r = t >> 4, c4 = t & 15;
    *(float4*)&draw[r][c4*4] = *(const float4*)(dbc + (size_t)(m0+r)*96 + c4*4);
  }
  float w[64];
  const float* wp = Wdt + (size_t)n*64;
#pragma unroll
  for (int k4 = 0; k4 < 16; ++k4) {
    float4 wv = *(const float4*)(wp + k4*4);
    w[k4*4+0] = wv.x; w[k4*4+1] = wv.y; w[k4*4+2] = wv.z; w[k4*4+3] = wv.w;
  }
  __syncthreads();
  const float bb = bdt[n];
#pragma unroll 4
  for (int r = 0; r < 16; ++r) {
    float s = bb;
#pragma unroll
    for (int k = 0; k < 64; ++k) s += draw[r][k]*w[k];
    float sp = (s > 20.f) ? s : log1pf(expf(s));
    delta[(size_t)(m0+r)*DI + n] = sp;
  }
}

// ---------------------------------------------------------------------------
// Sequential selective scan. One thread per (b, d). 4096 threads total.
// Reads delta, x (=ui[:, :2048]), z (=ui[:, 2048:]), B/C from dbc.
// Writes gated y in place into the z half of ui.
// grid = 16, block = 256
// ---------------------------------------------------------------------------
__global__ __launch_bounds__(256) void scan_kernel(
    float* __restrict__ ui,
    const float* __restrict__ dbc,
    const float* __restrict__ delta,
    const float* __restrict__ A_log,
    const float* __restrict__ Dp)
{
  const int gid = blockIdx.x*256 + threadIdx.x;  // 0..4095
  const int b = gid >> 11;
  const int d = gid & 2047;

  float A[NST];
#pragma unroll
  for (int nn = 0; nn < NST; ++nn) A[nn] = -expf(A_log[(size_t)d*NST + nn]);
  const float Dv = Dp[d];

  float h[NST];
#pragma unroll
  for (int nn = 0; nn < NST; ++nn) h[nn] = 0.f;

  const float* dptr = delta + (size_t)b*SEQ*DI + d;
  float*       uip  = ui    + (size_t)b*SEQ*4096;
  const float* cptr = dbc   + (size_t)b*SEQ*96;

  // prefetch t = 0
  float dt = dptr[0];
  float xv = uip[d];
  float zv = uip[2048 + d];
  float4 Bv0 = *(const float4*)(cptr + 64);
  float4 Bv1 = *(const float4*)(cptr + 68);
  float4 Bv2 = *(const float4*)(cptr + 72);
  float4 Bv3 = *(const float4*)(cptr + 76);
  float4 Cv0 = *(const float4*)(cptr + 80);
  float4 Cv1 = *(const float4*)(cptr + 84);
  float4 Cv2 = *(const float4*)(cptr + 88);
  float4 Cv3 = *(const float4*)(cptr + 92);

  for (int t = 0; t < SEQ; ++t) {
    const float dtc = dt, xvc = xv, zvc = zv;
    float Bc[NST] = {Bv0.x,Bv0.y,Bv0.z,Bv0.w, Bv1.x,Bv1.y,Bv1.z,Bv1.w,
                     Bv2.x,Bv2.y,Bv2.z,Bv2.w, Bv3.x,Bv3.y,Bv3.z,Bv3.w};
    float Cc[NST] = {Cv0.x,Cv0.y,Cv0.z,Cv0.w, Cv1.x,Cv1.y,Cv1.z,Cv1.w,
                     Cv2.x,Cv2.y,Cv2.z,Cv2.w, Cv3.x,Cv3.y,Cv3.z,Cv3.w};
    if (t + 1 < SEQ) {   // prefetch next iteration (overlaps the compute below)
      const size_t tn = (size_t)(t+1);
      dt = dptr[tn*DI];
      xv = uip[tn*4096 + d];
      zv = uip[tn*4096 + 2048 + d];
      const float* cp = cptr + tn*96;
      Bv0 = *(const float4*)(cp + 64);
      Bv1 = *(const float4*)(cp + 68);
      Bv2 = *(const float4*)(cp + 72);
      Bv3 = *(const float4*)(cp + 76);
      Cv0 = *(const float4*)(cp + 80);
      Cv1 = *(const float4*)(cp + 84);
      Cv2 = *(const float4*)(cp + 88);
      Cv3 = *(const float4*)(cp + 92);
    }
    const float xdt = xvc * dtc;
    float y = 0.f;
#pragma unroll
    for (int nn = 0; nn < NST; ++nn) {
      float dA = __expf(dtc * A[nn]);
      h[nn] = h[nn]*dA + xdt*Bc[nn];
      y += h[nn]*Cc[nn];
    }
    y += xvc * Dv;
    y *= zvc / (1.f + __expf(-zvc));          // * z*sigmoid(z)
    uip[(size_t)t*4096 + 2048 + d] = y;
  }
}

// ---------------------------------------------------------------------------
extern "C" void kernel_launch(void* const* d_in, const int* in_sizes, int n_in,
                              void* d_out, int out_size, void* d_ws, size_t ws_size,
                              hipStream_t stream)
{
  const float* u     = (const float*)d_in[0];
  const float* W_in  = (const float*)d_in[1];
  const float* b_in  = (const float*)d_in[2];
  const float* W_x   = (const float*)d_in[3];
  const float* b_x   = (const float*)d_in[4];
  const float* W_dt  = (const float*)d_in[5];
  const float* b_dt  = (const float*)d_in[6];
  const float* A_log = (const float*)d_in[7];
  const float* Dp    = (const float*)d_in[8];
  const float* W_out = (const float*)d_in[9];
  const float* b_out = (const float*)d_in[10];
  float* out = (float*)d_out;

  float* ui    = (float*)d_ws;                   // MT * 4096  (x | z->y)
  float* dbc   = ui  + (size_t)MT*4096;          // MT * 96
  float* delta = dbc + (size_t)MT*96;            // MT * DI

  // 1) ui = u @ W_in^T + b_in            (M=4096, N=4096, K=1024)
  sgemm_abT<<<dim3(32,32), 256, 0, stream>>>(u, DM, W_in, DM, b_in, ui, 2*DI, DM);

  // 2) dbc = x @ W_x^T + b_x             (M=4096, N=96, K=2048)
  dbc_kernel<<<MT/8, 128, 0, stream>>>(ui, W_x, b_x, dbc);

  // 3) delta = softplus(draw @ W_dt^T + b_dt)   (M=4096, N=2048, K=64)
  delta_kernel<<<dim3(DI/256, MT/16), 256, 0, stream>>>(dbc, W_dt, b_dt, delta);

  // 4) selective scan + skip + SiLU gate (in-place into z half of ui)
  scan_kernel<<<16, 256, 0, stream>>>(ui, dbc, delta, A_log, Dp);

  // 5) out = y @ W_out^T + b_out         (M=4096, N=1024, K=2048)
  sgemm_abT<<<dim3(8,32), 256, 0, stream>>>(ui + 2048, 2*DI, W_out, DI, b_out, out, DM, DI);
}

// Round 2
// 938.863 us; speedup vs baseline: 2.0056x; 2.0056x over previous
//
#include <hip/hip_runtime.h>
#include <math.h>

#define BATCH 2
#define SEQ   2048
#define DM    1024
#define DI    2048
#define NST   16
#define DR    64
#define MT    (BATCH*SEQ)   // 4096
#define CHK   32            // chunks along T
#define LCH   (SEQ/CHK)     // 64 steps per chunk

// ---------------------------------------------------------------------------
// SGEMM: C(M,N) = A(M,K,lda) @ B(N,K,ldb)^T + bias(N)
// 128x128 tile, BK=8, 256 threads, 8x8 micro-tile per thread.
// grid = (N/128, M/128)
// ---------------------------------------------------------------------------
__global__ __launch_bounds__(256) void sgemm_abT(
    const float* __restrict__ A, int lda,
    const float* __restrict__ B, int ldb,
    const float* __restrict__ bias,
    float* __restrict__ C, int ldc, int K)
{
  __shared__ float As[8][128];
  __shared__ float Bs[8][128];
  const int tid = threadIdx.x;
  const int tx = tid & 15, ty = tid >> 4;
  const int bx = blockIdx.x, by = blockIdx.y;
  const int arow = tid >> 1;          // 0..127
  const int acol = (tid & 1) * 4;     // 0 or 4
  const float* Ap = A + (size_t)(by*128 + arow)*lda + acol;
  const float* Bp = B + (size_t)(bx*128 + arow)*ldb + acol;

  float acc[8][8];
#pragma unroll
  for (int i = 0; i < 8; ++i)
#pragma unroll
    for (int j = 0; j < 8; ++j) acc[i][j] = 0.f;

  for (int k0 = 0; k0 < K; k0 += 8) {
    float4 av = *(const float4*)(Ap + k0);
    float4 bv = *(const float4*)(Bp + k0);
    __syncthreads();   // protect previous iteration's LDS reads
    As[acol+0][arow] = av.x; As[acol+1][arow] = av.y;
    As[acol+2][arow] = av.z; As[acol+3][arow] = av.w;
    Bs[acol+0][arow] = bv.x; Bs[acol+1][arow] = bv.y;
    Bs[acol+2][arow] = bv.z; Bs[acol+3][arow] = bv.w;
    __syncthreads();
#pragma unroll
    for (int k = 0; k < 8; ++k) {
      float4 a0 = *(const float4*)&As[k][ty*8];
      float4 a1 = *(const float4*)&As[k][ty*8+4];
      float4 b0 = *(const float4*)&Bs[k][tx*4];
      float4 b1 = *(const float4*)&Bs[k][tx*4+64];
      float fa[8] = {a0.x,a0.y,a0.z,a0.w,a1.x,a1.y,a1.z,a1.w};
      float fb[8] = {b0.x,b0.y,b0.z,b0.w,b1.x,b1.y,b1.z,b1.w};
#pragma unroll
      for (int i = 0; i < 8; ++i)
#pragma unroll
        for (int j = 0; j < 8; ++j)
          acc[i][j] += fa[i]*fb[j];
    }
  }

  const int n0 = bx*128 + tx*4;
  float4 bias0 = *(const float4*)(bias + n0);
  float4 bias1 = *(const float4*)(bias + n0 + 64);
#pragma unroll
  for (int i = 0; i < 8; ++i) {
    int row = by*128 + ty*8 + i;
    float4 c0 = {acc[i][0]+bias0.x, acc[i][1]+bias0.y,
                 acc[i][2]+bias0.z, acc[i][3]+bias0.w};
    float4 c1 = {acc[i][4]+bias1.x, acc[i][5]+bias1.y,
                 acc[i][6]+bias1.z, acc[i][7]+bias1.w};
    *(float4*)(C + (size_t)row*ldc + n0)      = c0;
    *(float4*)(C + (size_t)row*ldc + n0 + 64) = c1;
  }
}

// ---------------------------------------------------------------------------
// dbc(m, 0..95) = x_row(m) . W_x[n] + b_x[n];  x = ui[:, 0:2048]
// ---------------------------------------------------------------------------
__global__ __launch_bounds__(128) void dbc_kernel(
    const float* __restrict__ ui, const float* __restrict__ Wx,
    const float* __restrict__ bx, float* __restrict__ dbc)
{
  __shared__ float xrow[8][2048];   // 64 KiB
  const int m0 = blockIdx.x * 8;
  for (int i = threadIdx.x; i < 8*512; i += 128) {
    int r = i >> 9, c4 = i & 511;
    *(float4*)&xrow[r][c4*4] = *(const float4*)(ui + (size_t)(m0+r)*4096 + c4*4);
  }
  __syncthreads();
  const int n = threadIdx.x;
  if (n < 96) {
    const float* w = Wx + (size_t)n*2048;
    float s[8];
#pragma unroll
    for (int r = 0; r < 8; ++r) s[r] = 0.f;
    for (int k = 0; k < 2048; k += 4) {
      float4 wv = *(const float4*)(w + k);
#pragma unroll
      for (int r = 0; r < 8; ++r) {
        s[r] += xrow[r][k]*wv.x + xrow[r][k+1]*wv.y
              + xrow[r][k+2]*wv.z + xrow[r][k+3]*wv.w;
      }
    }
    float bb = bx[n];
#pragma unroll
    for (int r = 0; r < 8; ++r)
      dbc[(size_t)(m0+r)*96 + n] = s[r] + bb;
  }
}

// ---------------------------------------------------------------------------
// delta(m,n) = softplus( dbc[m, 0:64] . W_dt[n] + b_dt[n] )
// ---------------------------------------------------------------------------
__global__ __launch_bounds__(256) void delta_kernel(
    const float* __restrict__ dbc, const float* __restrict__ Wdt,
    const float* __restrict__ bdt, float* __restrict__ delta)
{
  __shared__ float draw[16][64];
  const int n  = blockIdx.x * 256 + threadIdx.x;
  const int m0 = blockIdx.y * 16;
  {
    int t = threadIdx.x;           // 256 float4 = 16 rows x 16 float4
    int r = t >> 4, c4 = t & 15;
    *(float4*)&draw[r][c4*4] = *(const float4*)(dbc + (size_t)(m0+r)*96 + c4*4);
  }
  float w[64];
  const float* wp = Wdt + (size_t)n*64;
#pragma unroll
  for (int k4 = 0; k4 < 16; ++k4) {
    float4 wv = *(const float4*)(wp + k4*4);
    w[k4*4+0] = wv.x; w[k4*4+1] = wv.y; w[k4*4+2] = wv.z; w[k4*4+3] = wv.w;
  }
  __syncthreads();
  const float bb = bdt[n];
#pragma unroll 4
  for (int r = 0; r < 16; ++r) {
    float s = bb;
#pragma unroll
    for (int k = 0; k < 64; ++k) s += draw[r][k]*w[k];
    float sp = (s > 20.f) ? s : log1pf(expf(s));
    delta[(size_t)(m0+r)*DI + n] = sp;
  }
}

// ---------------------------------------------------------------------------
// Chunked scan, pass A: per (b, chunk, d) local scan from h=0.
// Emits P[b,c,d,n] = exp(A[n] * sum_chunk(dt))  and  S[b,c,d,n] = h_local_end.
// grid: B*CHK*DI / 256 = 512 blocks.
// ---------------------------------------------------------------------------
__global__ __launch_bounds__(256) void scanA_kernel(
    const float* __restrict__ ui,
    const float* __restrict__ dbc,
    const float* __restrict__ delta,
    const float* __restrict__ A_log,
    float* __restrict__ P,
    float* __restrict__ S)
{
  const int gid = blockIdx.x*256 + threadIdx.x;   // 0 .. B*CHK*DI-1
  const int d   = gid & (DI-1);
  const int rem = gid >> 11;
  const int c   = rem & (CHK-1);
  const int b   = rem >> 5;

  float A[NST];
  {
    const float4* ap = (const float4*)(A_log + (size_t)d*NST);
#pragma unroll
    for (int q = 0; q < 4; ++q) {
      float4 v = ap[q];
      A[q*4+0] = -expf(v.x); A[q*4+1] = -expf(v.y);
      A[q*4+2] = -expf(v.z); A[q*4+3] = -expf(v.w);
    }
  }

  float h[NST];
#pragma unroll
  for (int nn = 0; nn < NST; ++nn) h[nn] = 0.f;
  float sdt = 0.f;

  const int t0 = c * LCH;
  const float* dptr = delta + ((size_t)b*SEQ + t0)*DI + d;
  const float* xptr = ui    + ((size_t)b*SEQ + t0)*4096 + d;
  const float* bptr = dbc   + ((size_t)b*SEQ + t0)*96 + 64;

  float dt = dptr[0];
  float xv = xptr[0];
  float4 Bv0 = *(const float4*)(bptr + 0);
  float4 Bv1 = *(const float4*)(bptr + 4);
  float4 Bv2 = *(const float4*)(bptr + 8);
  float4 Bv3 = *(const float4*)(bptr + 12);

  for (int t = 0; t < LCH; ++t) {
    const float dtc = dt, xvc = xv;
    float Bc[NST] = {Bv0.x,Bv0.y,Bv0.z,Bv0.w, Bv1.x,Bv1.y,Bv1.z,Bv1.w,
                     Bv2.x,Bv2.y,Bv2.z,Bv2.w, Bv3.x,Bv3.y,Bv3.z,Bv3.w};
    if (t + 1 < LCH) {
      const size_t tn = (size_t)(t+1);
      dt = dptr[tn*DI];
      xv = xptr[tn*4096];
      const float* bp = bptr + tn*96;
      Bv0 = *(const float4*)(bp + 0);
      Bv1 = *(const float4*)(bp + 4);
      Bv2 = *(const float4*)(bp + 8);
      Bv3 = *(const float4*)(bp + 12);
    }
    sdt += dtc;
    const float xdt = xvc * dtc;
#pragma unroll
    for (int nn = 0; nn < NST; ++nn) {
      float dA = __expf(dtc * A[nn]);
      h[nn] = h[nn]*dA + xdt*Bc[nn];
    }
  }

  float* Pp = P + (((size_t)b*CHK + c)*DI + d)*NST;
  float* Sp = S + (((size_t)b*CHK + c)*DI + d)*NST;
#pragma unroll
  for (int q = 0; q < 4; ++q) {
    float4 pv = { __expf(A[q*4+0]*sdt), __expf(A[q*4+1]*sdt),
                  __expf(A[q*4+2]*sdt), __expf(A[q*4+3]*sdt) };
    float4 sv = { h[q*4+0], h[q*4+1], h[q*4+2], h[q*4+3] };
    *(float4*)(Pp + q*4) = pv;
    *(float4*)(Sp + q*4) = sv;
  }
}

// ---------------------------------------------------------------------------
// Chunked scan, pass B: inter-chunk scan over CHK steps, in place.
// S[b,c,d,:] is replaced by the carry-in state h_in for chunk c.
// One thread per (b, d, n4): B*DI*4 = 16384 threads.
// ---------------------------------------------------------------------------
__global__ __launch_bounds__(256) void scanB_kernel(
    const float* __restrict__ P, float* __restrict__ S)
{
  const int gid = blockIdx.x*256 + threadIdx.x;
  const int n4 = gid & 3;
  const int d  = (gid >> 2) & (DI-1);
  const int b  = gid >> 13;

  float4 h = {0.f, 0.f, 0.f, 0.f};
  for (int c = 0; c < CHK; ++c) {
    const size_t idx = (((size_t)b*CHK + c)*DI + d)*NST + n4*4;
    float4 p = *(const float4*)(P + idx);
    float4 s = *(const float4*)(S + idx);
    *(float4*)(S + idx) = h;             // carry-in for chunk c
    h.x = h.x*p.x + s.x;
    h.y = h.y*p.y + s.y;
    h.z = h.z*p.z + s.z;
    h.w = h.w*p.w + s.w;
  }
}

// ---------------------------------------------------------------------------
// Chunked scan, pass C: re-run local scan seeded with carry-in, compute y,
// add skip, apply SiLU(z) gate, write into z half of ui.
// ---------------------------------------------------------------------------
__global__ __launch_bounds__(256) void scanC_kernel(
    float* __restrict__ ui,
    const float* __restrict__ dbc,
    const float* __restrict__ delta,
    const float* __restrict__ A_log,
    const float* __restrict__ Dp,
    const float* __restrict__ S)
{
  const int gid = blockIdx.x*256 + threadIdx.x;
  const int d   = gid & (DI-1);
  const int rem = gid >> 11;
  const int c   = rem & (CHK-1);
  const int b   = rem >> 5;

  float A[NST];
  {
    const float4* ap = (const float4*)(A_log + (size_t)d*NST);
#pragma unroll
    for (int q = 0; q < 4; ++q) {
      float4 v = ap[q];
      A[q*4+0] = -expf(v.x); A[q*4+1] = -expf(v.y);
      A[q*4+2] = -expf(v.z); A[q*4+3] = -expf(v.w);
    }
  }
  const float Dv = Dp[d];

  float h[NST];
  {
    const float* Sp = S + (((size_t)b*CHK + c)*DI + d)*NST;
#pragma unroll
    for (int q = 0; q < 4; ++q) {
      float4 sv = *(const float4*)(Sp + q*4);
      h[q*4+0] = sv.x; h[q*4+1] = sv.y; h[q*4+2] = sv.z; h[q*4+3] = sv.w;
    }
  }

  const int t0 = c * LCH;
  const float* dptr = delta + ((size_t)b*SEQ + t0)*DI + d;
  float*       uip  = ui    + ((size_t)b*SEQ + t0)*4096;
  const float* cptr = dbc   + ((size_t)b*SEQ + t0)*96;

  float dt = dptr[0];
  float xv = uip[d];
  float zv = uip[2048 + d];
  float4 Bv0 = *(const float4*)(cptr + 64);
  float4 Bv1 = *(const float4*)(cptr + 68);
  float4 Bv2 = *(const float4*)(cptr + 72);
  float4 Bv3 = *(const float4*)(cptr + 76);
  float4 Cv0 = *(const float4*)(cptr + 80);
  float4 Cv1 = *(const float4*)(cptr + 84);
  float4 Cv2 = *(const float4*)(cptr + 88);
  float4 Cv3 = *(const float4*)(cptr + 92);

  for (int t = 0; t < LCH; ++t) {
    const float dtc = dt, xvc = xv, zvc = zv;
    float Bc[NST] = {Bv0.x,Bv0.y,Bv0.z,Bv0.w, Bv1.x,Bv1.y,Bv1.z,Bv1.w,
                     Bv2.x,Bv2.y,Bv2.z,Bv2.w, Bv3.x,Bv3.y,Bv3.z,Bv3.w};
    float Cc[NST] = {Cv0.x,Cv0.y,Cv0.z,Cv0.w, Cv1.x,Cv1.y,Cv1.z,Cv1.w,
                     Cv2.x,Cv2.y,Cv2.z,Cv2.w, Cv3.x,Cv3.y,Cv3.z,Cv3.w};
    if (t + 1 < LCH) {
      const size_t tn = (size_t)(t+1);
      dt = dptr[tn*DI];
      xv = uip[tn*4096 + d];
      zv = uip[tn*4096 + 2048 + d];
      const float* cp = cptr + tn*96;
      Bv0 = *(const float4*)(cp + 64);
      Bv1 = *(const float4*)(cp + 68);
      Bv2 = *(const float4*)(cp + 72);
      Bv3 = *(const float4*)(cp + 76);
      Cv0 = *(const float4*)(cp + 80);
      Cv1 = *(const float4*)(cp + 84);
      Cv2 = *(const float4*)(cp + 88);
      Cv3 = *(const float4*)(cp + 92);
    }
    const float xdt = xvc * dtc;
    float y = 0.f;
#pragma unroll
    for (int nn = 0; nn < NST; ++nn) {
      float dA = __expf(dtc * A[nn]);
      h[nn] = h[nn]*dA + xdt*Bc[nn];
      y += h[nn]*Cc[nn];
    }
    y += xvc * Dv;
    y *= zvc / (1.f + __expf(-zvc));          // * z*sigmoid(z)
    uip[(size_t)t*4096 + 2048 + d] = y;
  }
}

// ---------------------------------------------------------------------------
extern "C" void kernel_launch(void* const* d_in, const int* in_sizes, int n_in,
                              void* d_out, int out_size, void* d_ws, size_t ws_size,
                              hipStream_t stream)
{
  const float* u     = (const float*)d_in[0];
  const float* W_in  = (const float*)d_in[1];
  const float* b_in  = (const float*)d_in[2];
  const float* W_x   = (const float*)d_in[3];
  const float* b_x   = (const float*)d_in[4];
  const float* W_dt  = (const float*)d_in[5];
  const float* b_dt  = (const float*)d_in[6];
  const float* A_log = (const float*)d_in[7];
  const float* Dp    = (const float*)d_in[8];
  const float* W_out = (const float*)d_in[9];
  const float* b_out = (const float*)d_in[10];
  float* out = (float*)d_out;

  float* ui    = (float*)d_ws;                   // MT * 4096  (x | z->y)
  float* dbc   = ui  + (size_t)MT*4096;          // MT * 96
  float* delta = dbc + (size_t)MT*96;            // MT * DI

  // P and S live in d_out (dead until stage 5): exactly 2*B*CHK*DI*NST =
  // 4,194,304 floats = out_size.
  float* P = out;                                 // B*CHK*DI*NST
  float* S = P + (size_t)BATCH*CHK*DI*NST;        // B*CHK*DI*NST

  // 1) ui = u @ W_in^T + b_in            (M=4096, N=4096, K=1024)
  sgemm_abT<<<dim3(32,32), 256, 0, stream>>>(u, DM, W_in, DM, b_in, ui, 2*DI, DM);

  // 2) dbc = x @ W_x^T + b_x             (M=4096, N=96, K=2048)
  dbc_kernel<<<MT/8, 128, 0, stream>>>(ui, W_x, b_x, dbc);

  // 3) delta = softplus(draw @ W_dt^T + b_dt)   (M=4096, N=2048, K=64)
  delta_kernel<<<dim3(DI/256, MT/16), 256, 0, stream>>>(dbc, W_dt, b_dt, delta);

  // 4) chunk-parallel selective scan
  scanA_kernel<<<BATCH*CHK*DI/256, 256, 0, stream>>>(ui, dbc, delta, A_log, P, S);
  scanB_kernel<<<BATCH*DI*4/256, 256, 0, stream>>>(P, S);
  scanC_kernel<<<BATCH*CHK*DI/256, 256, 0, stream>>>(ui, dbc, delta, A_log, Dp, S);

  // 5) out = y @ W_out^T + b_out         (M=4096, N=1024, K=2048)
  sgemm_abT<<<dim3(8,32), 256, 0, stream>>>(ui + 2048, 2*DI, W_out, DI, b_out, out, DM, DI);
}

// Round 3
// 338.205 us; speedup vs baseline: 5.5676x; 2.7760x over previous
//
#include <hip/hip_runtime.h>
#include <math.h>

#define BATCH 2
#define SEQ   2048
#define DM    1024
#define DI    2048
#define NST   16
#define MT    (BATCH*SEQ)   // 4096
#define CHK   32            // chunks along T
#define LCH   (SEQ/CHK)     // 64 steps per chunk

typedef __attribute__((ext_vector_type(8))) short  bf16x8;
typedef __attribute__((ext_vector_type(4))) float  f32x4;

static __device__ __forceinline__ unsigned short f2bf(float f) {
  unsigned u = __float_as_uint(f);
  u += 0x7fff + ((u >> 16) & 1);          // RNE
  return (unsigned short)(u >> 16);
}
static __device__ __forceinline__ float bf2f(unsigned short h) {
  return __uint_as_float(((unsigned)h) << 16);
}

// ---------------------------------------------------------------------------
// fp32 -> bf16 bulk convert (float4 in, ushort4 out)
// ---------------------------------------------------------------------------
__global__ __launch_bounds__(256) void conv_bf16_kernel(
    const float* __restrict__ src, unsigned short* __restrict__ dst, int n4)
{
  int i = blockIdx.x * 256 + threadIdx.x;
  if (i < n4) {
    float4 v = ((const float4*)src)[i];
    ushort4 o;
    o.x = f2bf(v.x); o.y = f2bf(v.y); o.z = f2bf(v.z); o.w = f2bf(v.w);
    ((ushort4*)dst)[i] = o;
  }
}

// ---------------------------------------------------------------------------
// bf16 MFMA GEMM: C(M,N) = A(M,K) @ B(N,K)^T + bias(N)
// A,B bf16 row-major (K contiguous). 128x128 tile, BK=32, 256 thr = 4 waves
// (2x2), each wave 64x64 out = 4x4 frags of 16x16x32 MFMA.
// LDS XOR-swizzle: slot = c8 ^ ((row>>1)&3) applied on the global SOURCE
// (global_load_lds writes linearly) and on the read side.
// grid = nbx*nby (1D, XCD-swizzled); nbx = N/128.
// ---------------------------------------------------------------------------
template<int LDC, bool OUT_BF16>
__global__ __launch_bounds__(256) void gemm_bf16_kernel(
    const unsigned short* __restrict__ A,
    const unsigned short* __restrict__ B,
    const float* __restrict__ bias,
    void* __restrict__ Cout, int K, int nbx)
{
  __shared__ unsigned short Abuf[128*32];
  __shared__ unsigned short Bbuf[128*32];

  // XCD-aware block swizzle (grid % 8 == 0 for both uses)
  const int nwg = gridDim.x;
  const int cpx = nwg >> 3;
  const int bid = blockIdx.x;
  const int swz = (bid & 7) * cpx + (bid >> 3);
  const int bx = swz % nbx;
  const int by = swz / nbx;

  const int tid  = threadIdx.x;
  const int lane = tid & 63;
  const int wid  = tid >> 6;
  const int wr   = wid >> 1;    // wave row (0..1)
  const int wc   = wid & 1;     // wave col (0..1)

  const int lr    = lane >> 2;  // staging: row within 16-row group
  const int lslot = lane & 3;   // staging: 16B slot within row

  f32x4 zero = {0.f, 0.f, 0.f, 0.f};
  f32x4 acc[4][4];
#pragma unroll
  for (int i = 0; i < 4; ++i)
#pragma unroll
    for (int j = 0; j < 4; ++j) acc[i][j] = zero;

  const size_t arow0 = (size_t)by * 128;
  const size_t brow0 = (size_t)bx * 128;

  for (int k0 = 0; k0 < K; k0 += 32) {
#pragma unroll
    for (int i = 0; i < 2; ++i) {
      const int Rb = wid*32 + i*16;             // wave-uniform base row
      const int r  = Rb + lr;
      const int c8 = lslot ^ ((r >> 1) & 3);    // pre-swizzled global source
      const unsigned short* ga = A + (arow0 + r)*(size_t)K + k0 + c8*8;
      const unsigned short* gb = B + (brow0 + r)*(size_t)K + k0 + c8*8;
      __builtin_amdgcn_global_load_lds(
          (const __attribute__((address_space(1))) void*)ga,
          (__attribute__((address_space(3))) void*)(Abuf + Rb*32), 16, 0, 0);
      __builtin_amdgcn_global_load_lds(
          (const __attribute__((address_space(1))) void*)gb,
          (__attribute__((address_space(3))) void*)(Bbuf + Rb*32), 16, 0, 0);
    }
    __syncthreads();   // vmcnt(0) drain + barrier

    const int lrow = lane & 15, k8 = lane >> 4;
    bf16x8 af[4], bfr[4];
#pragma unroll
    for (int mi = 0; mi < 4; ++mi) {
      int r = wr*64 + mi*16 + lrow;
      af[mi] = *(const bf16x8*)&Abuf[r*32 + (k8 ^ ((r >> 1) & 3))*8];
    }
#pragma unroll
    for (int nj = 0; nj < 4; ++nj) {
      int r = wc*64 + nj*16 + lrow;
      bfr[nj] = *(const bf16x8*)&Bbuf[r*32 + (k8 ^ ((r >> 1) & 3))*8];
    }
#pragma unroll
    for (int mi = 0; mi < 4; ++mi)
#pragma unroll
      for (int nj = 0; nj < 4; ++nj)
        acc[mi][nj] = __builtin_amdgcn_mfma_f32_16x16x32_bf16(
                          af[mi], bfr[nj], acc[mi][nj], 0, 0, 0);
    __syncthreads();
  }

  // epilogue: C/D layout col=lane&15, row=(lane>>4)*4+q  [m89]
  const int lcol = lane & 15, lrq = lane >> 4;
#pragma unroll
  for (int nj = 0; nj < 4; ++nj) {
    const int colg = bx*128 + wc*64 + nj*16 + lcol;
    const float bv = bias[colg];
#pragma unroll
    for (int mi = 0; mi < 4; ++mi) {
      const int rowg = by*128 + wr*64 + mi*16 + lrq*4;
#pragma unroll
      for (int q = 0; q < 4; ++q) {
        float v = acc[mi][nj][q] + bv;
        if constexpr (OUT_BF16)
          ((unsigned short*)Cout)[(size_t)(rowg + q)*LDC + colg] = f2bf(v);
        else
          ((float*)Cout)[(size_t)(rowg + q)*LDC + colg] = v;
      }
    }
  }
}

// ---------------------------------------------------------------------------
// dbc(m, 0..95) = x_row(m) . W_x[n] + b_x[n];  x = ui_bf[:, 0:2048] (bf16)
// ---------------------------------------------------------------------------
__global__ __launch_bounds__(128) void dbc_kernel(
    const unsigned short* __restrict__ uib, const float* __restrict__ Wx,
    const float* __restrict__ bx, float* __restrict__ dbc)
{
  __shared__ float xrow[8][2048];   // 64 KiB
  const int m0 = blockIdx.x * 8;
  for (int i = threadIdx.x; i < 8*256; i += 128) {
    int r = i >> 8, c8 = i & 255;
    bf16x8 v = *(const bf16x8*)(uib + (size_t)(m0+r)*4096 + c8*8);
#pragma unroll
    for (int q = 0; q < 8; ++q)
      xrow[r][c8*8 + q] = bf2f((unsigned short)v[q]);
  }
  __syncthreads();
  const int n = threadIdx.x;
  if (n < 96) {
    const float* w = Wx + (size_t)n*2048;
    float s[8];
#pragma unroll
    for (int r = 0; r < 8; ++r) s[r] = 0.f;
    for (int k = 0; k < 2048; k += 4) {
      float4 wv = *(const float4*)(w + k);
#pragma unroll
      for (int r = 0; r < 8; ++r) {
        s[r] += xrow[r][k]*wv.x + xrow[r][k+1]*wv.y
              + xrow[r][k+2]*wv.z + xrow[r][k+3]*wv.w;
      }
    }
    float bb = bx[n];
#pragma unroll
    for (int r = 0; r < 8; ++r)
      dbc[(size_t)(m0+r)*96 + n] = s[r] + bb;
  }
}

// ---------------------------------------------------------------------------
// delta(m,n) = softplus( dbc[m, 0:64] . W_dt[n] + b_dt[n] )
// ---------------------------------------------------------------------------
__global__ __launch_bounds__(256) void delta_kernel(
    const float* __restrict__ dbc, const float* __restrict__ Wdt,
    const float* __restrict__ bdt, float* __restrict__ delta)
{
  __shared__ float draw[16][64];
  const int n  = blockIdx.x * 256 + threadIdx.x;
  const int m0 = blockIdx.y * 16;
  {
    int t = threadIdx.x;
    int r = t >> 4, c4 = t & 15;
    *(float4*)&draw[r][c4*4] = *(const float4*)(dbc + (size_t)(m0+r)*96 + c4*4);
  }
  float w[64];
  const float* wp = Wdt + (size_t)n*64;
#pragma unroll
  for (int k4 = 0; k4 < 16; ++k4) {
    float4 wv = *(const float4*)(wp + k4*4);
    w[k4*4+0] = wv.x; w[k4*4+1] = wv.y; w[k4*4+2] = wv.z; w[k4*4+3] = wv.w;
  }
  __syncthreads();
  const float bb = bdt[n];
#pragma unroll 4
  for (int r = 0; r < 16; ++r) {
    float s = bb;
#pragma unroll
    for (int k = 0; k < 64; ++k) s += draw[r][k]*w[k];
    float sp = (s > 20.f) ? s : log1pf(expf(s));
    delta[(size_t)(m0+r)*DI + n] = sp;
  }
}

// ---------------------------------------------------------------------------
// Chunked scan, pass A: local scan from h=0; emits P = exp(A*sum dt), S = h_end
// ---------------------------------------------------------------------------
__global__ __launch_bounds__(256) void scanA_kernel(
    const unsigned short* __restrict__ uib,
    const float* __restrict__ dbc,
    const float* __restrict__ delta,
    const float* __restrict__ A_log,
    float* __restrict__ P,
    float* __restrict__ S)
{
  const int gid = blockIdx.x*256 + threadIdx.x;
  const int d   = gid & (DI-1);
  const int rem = gid >> 11;
  const int c   = rem & (CHK-1);
  const int b   = rem >> 5;

  float A[NST];
  {
    const float4* ap = (const float4*)(A_log + (size_t)d*NST);
#pragma unroll
    for (int q = 0; q < 4; ++q) {
      float4 v = ap[q];
      A[q*4+0] = -expf(v.x); A[q*4+1] = -expf(v.y);
      A[q*4+2] = -expf(v.z); A[q*4+3] = -expf(v.w);
    }
  }

  float h[NST];
#pragma unroll
  for (int nn = 0; nn < NST; ++nn) h[nn] = 0.f;
  float sdt = 0.f;

  const int t0 = c * LCH;
  const float* dptr          = delta + ((size_t)b*SEQ + t0)*DI + d;
  const unsigned short* xptr = uib   + ((size_t)b*SEQ + t0)*4096 + d;
  const float* bptr          = dbc   + ((size_t)b*SEQ + t0)*96 + 64;

  float dt = dptr[0];
  float xv = bf2f(xptr[0]);
  float4 Bv0 = *(const float4*)(bptr + 0);
  float4 Bv1 = *(const float4*)(bptr + 4);
  float4 Bv2 = *(const float4*)(bptr + 8);
  float4 Bv3 = *(const float4*)(bptr + 12);

  for (int t = 0; t < LCH; ++t) {
    const float dtc = dt, xvc = xv;
    float Bc[NST] = {Bv0.x,Bv0.y,Bv0.z,Bv0.w, Bv1.x,Bv1.y,Bv1.z,Bv1.w,
                     Bv2.x,Bv2.y,Bv2.z,Bv2.w, Bv3.x,Bv3.y,Bv3.z,Bv3.w};
    if (t + 1 < LCH) {
      const size_t tn = (size_t)(t+1);
      dt = dptr[tn*DI];
      xv = bf2f(xptr[tn*4096]);
      const float* bp = bptr + tn*96;
      Bv0 = *(const float4*)(bp + 0);
      Bv1 = *(const float4*)(bp + 4);
      Bv2 = *(const float4*)(bp + 8);
      Bv3 = *(const float4*)(bp + 12);
    }
    sdt += dtc;
    const float xdt = xvc * dtc;
#pragma unroll
    for (int nn = 0; nn < NST; ++nn) {
      float dA = __expf(dtc * A[nn]);
      h[nn] = h[nn]*dA + xdt*Bc[nn];
    }
  }

  float* Pp = P + (((size_t)b*CHK + c)*DI + d)*NST;
  float* Sp = S + (((size_t)b*CHK + c)*DI + d)*NST;
#pragma unroll
  for (int q = 0; q < 4; ++q) {
    float4 pv = { __expf(A[q*4+0]*sdt), __expf(A[q*4+1]*sdt),
                  __expf(A[q*4+2]*sdt), __expf(A[q*4+3]*sdt) };
    float4 sv = { h[q*4+0], h[q*4+1], h[q*4+2], h[q*4+3] };
    *(float4*)(Pp + q*4) = pv;
    *(float4*)(Sp + q*4) = sv;
  }
}

// ---------------------------------------------------------------------------
// Chunked scan, pass B: inter-chunk scan; S replaced by carry-in state.
// ---------------------------------------------------------------------------
__global__ __launch_bounds__(256) void scanB_kernel(
    const float* __restrict__ P, float* __restrict__ S)
{
  const int gid = blockIdx.x*256 + threadIdx.x;
  const int n4 = gid & 3;
  const int d  = (gid >> 2) & (DI-1);
  const int b  = gid >> 13;

  float4 h = {0.f, 0.f, 0.f, 0.f};
  for (int c = 0; c < CHK; ++c) {
    const size_t idx = (((size_t)b*CHK + c)*DI + d)*NST + n4*4;
    float4 p = *(const float4*)(P + idx);
    float4 s = *(const float4*)(S + idx);
    *(float4*)(S + idx) = h;
    h.x = h.x*p.x + s.x;
    h.y = h.y*p.y + s.y;
    h.z = h.z*p.z + s.z;
    h.w = h.w*p.w + s.w;
  }
}

// ---------------------------------------------------------------------------
// Chunked scan, pass C: seeded local scan; y + skip + SiLU gate -> y_bf (bf16)
// ---------------------------------------------------------------------------
__global__ __launch_bounds__(256) void scanC_kernel(
    const unsigned short* __restrict__ uib,
    const float* __restrict__ dbc,
    const float* __restrict__ delta,
    const float* __restrict__ A_log,
    const float* __restrict__ Dp,
    const float* __restrict__ S,
    unsigned short* __restrict__ y_bf)
{
  const int gid = blockIdx.x*256 + threadIdx.x;
  const int d   = gid & (DI-1);
  const int rem = gid >> 11;
  const int c   = rem & (CHK-1);
  const int b   = rem >> 5;

  float A[NST];
  {
    const float4* ap = (const float4*)(A_log + (size_t)d*NST);
#pragma unroll
    for (int q = 0; q < 4; ++q) {
      float4 v = ap[q];
      A[q*4+0] = -expf(v.x); A[q*4+1] = -expf(v.y);
      A[q*4+2] = -expf(v.z); A[q*4+3] = -expf(v.w);
    }
  }
  const float Dv = Dp[d];

  float h[NST];
  {
    const float* Sp = S + (((size_t)b*CHK + c)*DI + d)*NST;
#pragma unroll
    for (int q = 0; q < 4; ++q) {
      float4 sv = *(const float4*)(Sp + q*4);
      h[q*4+0] = sv.x; h[q*4+1] = sv.y; h[q*4+2] = sv.z; h[q*4+3] = sv.w;
    }
  }

  const int t0 = c * LCH;
  const float* dptr          = delta + ((size_t)b*SEQ + t0)*DI + d;
  const unsigned short* xptr = uib   + ((size_t)b*SEQ + t0)*4096 + d;
  const float* cptr          = dbc   + ((size_t)b*SEQ + t0)*96;
  unsigned short* yp         = y_bf  + ((size_t)b*SEQ + t0)*DI + d;

  float dt = dptr[0];
  float xv = bf2f(xptr[0]);
  float zv = bf2f(xptr[2048]);
  float4 Bv0 = *(const float4*)(cptr + 64);
  float4 Bv1 = *(const float4*)(cptr + 68);
  float4 Bv2 = *(const float4*)(cptr + 72);
  float4 Bv3 = *(const float4*)(cptr + 76);
  float4 Cv0 = *(const float4*)(cptr + 80);
  float4 Cv1 = *(const float4*)(cptr + 84);
  float4 Cv2 = *(const float4*)(cptr + 88);
  float4 Cv3 = *(const float4*)(cptr + 92);

  for (int t = 0; t < LCH; ++t) {
    const float dtc = dt, xvc = xv, zvc = zv;
    float Bc[NST] = {Bv0.x,Bv0.y,Bv0.z,Bv0.w, Bv1.x,Bv1.y,Bv1.z,Bv1.w,
                     Bv2.x,Bv2.y,Bv2.z,Bv2.w, Bv3.x,Bv3.y,Bv3.z,Bv3.w};
    float Cc[NST] = {Cv0.x,Cv0.y,Cv0.z,Cv0.w, Cv1.x,Cv1.y,Cv1.z,Cv1.w,
                     Cv2.x,Cv2.y,Cv2.z,Cv2.w, Cv3.x,Cv3.y,Cv3.z,Cv3.w};
    if (t + 1 < LCH) {
      const size_t tn = (size_t)(t+1);
      dt = dptr[tn*DI];
      xv = bf2f(xptr[tn*4096]);
      zv = bf2f(xptr[tn*4096 + 2048]);
      const float* cp = cptr + tn*96;
      Bv0 = *(const float4*)(cp + 64);
      Bv1 = *(const float4*)(cp + 68);
      Bv2 = *(const float4*)(cp + 72);
      Bv3 = *(const float4*)(cp + 76);
      Cv0 = *(const float4*)(cp + 80);
      Cv1 = *(const float4*)(cp + 84);
      Cv2 = *(const float4*)(cp + 88);
      Cv3 = *(const float4*)(cp + 92);
    }
    const float xdt = xvc * dtc;
    float y = 0.f;
#pragma unroll
    for (int nn = 0; nn < NST; ++nn) {
      float dA = __expf(dtc * A[nn]);
      h[nn] = h[nn]*dA + xdt*Bc[nn];
      y += h[nn]*Cc[nn];
    }
    y += xvc * Dv;
    y *= zvc / (1.f + __expf(-zvc));
    yp[(size_t)t*DI] = f2bf(y);
  }
}

// ---------------------------------------------------------------------------
extern "C" void kernel_launch(void* const* d_in, const int* in_sizes, int n_in,
                              void* d_out, int out_size, void* d_ws, size_t ws_size,
                              hipStream_t stream)
{
  const float* u     = (const float*)d_in[0];
  const float* W_in  = (const float*)d_in[1];
  const float* b_in  = (const float*)d_in[2];
  const float* W_x   = (const float*)d_in[3];
  const float* b_x   = (const float*)d_in[4];
  const float* W_dt  = (const float*)d_in[5];
  const float* b_dt  = (const float*)d_in[6];
  const float* A_log = (const float*)d_in[7];
  const float* Dp    = (const float*)d_in[8];
  const float* W_out = (const float*)d_in[9];
  const float* b_out = (const float*)d_in[10];
  float* out = (float*)d_out;

  // workspace (89.6 MB total)
  unsigned short* ui_bf   = (unsigned short*)d_ws;            // MT*4096 bf16
  float*          dbc     = (float*)(ui_bf + (size_t)MT*4096);// MT*96 f32
  float*          delta   = dbc + (size_t)MT*96;              // MT*DI f32
  unsigned short* y_bf    = (unsigned short*)(delta + (size_t)MT*DI); // MT*DI bf16
  unsigned short* wout_bf = y_bf + (size_t)MT*DI;             // DM*DI bf16

  // d_out doubles as scratch: u_bf+Win_bf (before scanA), then P+S, then out
  unsigned short* u_bf   = (unsigned short*)d_out;            // MT*DM bf16
  unsigned short* win_bf = u_bf + (size_t)MT*DM;              // 2DI*DM bf16
  float* P = (float*)d_out;                                   // B*CHK*DI*NST
  float* S = P + (size_t)BATCH*CHK*DI*NST;

  // 0) fp32 -> bf16 conversions
  conv_bf16_kernel<<<4096, 256, 0, stream>>>(u,     u_bf,    MT*DM/4);
  conv_bf16_kernel<<<4096, 256, 0, stream>>>(W_in,  win_bf,  2*DI*DM/4);
  conv_bf16_kernel<<<2048, 256, 0, stream>>>(W_out, wout_bf, DM*DI/4);

  // 1) ui = u @ W_in^T + b_in   (M=4096, N=4096, K=1024) -> bf16
  gemm_bf16_kernel<4096, true><<<32*32, 256, 0, stream>>>(
      u_bf, win_bf, b_in, ui_bf, DM, 32);

  // 2) dbc = x @ W_x^T + b_x    (N=96, K=2048)
  dbc_kernel<<<MT/8, 128, 0, stream>>>(ui_bf, W_x, b_x, dbc);

  // 3) delta = softplus(draw @ W_dt^T + b_dt)
  delta_kernel<<<dim3(DI/256, MT/16), 256, 0, stream>>>(dbc, W_dt, b_dt, delta);

  // 4) chunk-parallel selective scan (P,S overwrite u_bf/win_bf — dead now)
  scanA_kernel<<<BATCH*CHK*DI/256, 256, 0, stream>>>(ui_bf, dbc, delta, A_log, P, S);
  scanB_kernel<<<BATCH*DI*4/256, 256, 0, stream>>>(P, S);
  scanC_kernel<<<BATCH*CHK*DI/256, 256, 0, stream>>>(ui_bf, dbc, delta, A_log, Dp, S, y_bf);

  // 5) out = y @ W_out^T + b_out (M=4096, N=1024, K=2048) -> f32 (overwrites P,S)
  gemm_bf16_kernel<1024, false><<<8*32, 256, 0, stream>>>(
      y_bf, wout_bf, b_out, out, DI, 8);
}

// Round 4
// 284.344 us; speedup vs baseline: 6.6222x; 1.1894x over previous
//
#include <hip/hip_runtime.h>
#include <math.h>

#define BATCH 2
#define SEQ   2048
#define DM    1024
#define DI    2048
#define NST   16
#define MT    (BATCH*SEQ)   // 4096
#define CHK   32            // chunks along T
#define LCH   (SEQ/CHK)     // 64 steps per chunk

typedef __attribute__((ext_vector_type(8))) short  bf16x8;
typedef __attribute__((ext_vector_type(4))) float  f32x4;

static __device__ __forceinline__ unsigned short f2bf(float f) {
  unsigned u = __float_as_uint(f);
  u += 0x7fff + ((u >> 16) & 1);          // RNE
  return (unsigned short)(u >> 16);
}
static __device__ __forceinline__ float bf2f(unsigned short h) {
  return __uint_as_float(((unsigned)h) << 16);
}

// ---------------------------------------------------------------------------
// fp32 -> bf16 bulk convert (float4 in, ushort4 out)
// ---------------------------------------------------------------------------
__global__ __launch_bounds__(256) void conv_bf16_kernel(
    const float* __restrict__ src, unsigned short* __restrict__ dst, int n4)
{
  int i = blockIdx.x * 256 + threadIdx.x;
  if (i < n4) {
    float4 v = ((const float4*)src)[i];
    ushort4 o;
    o.x = f2bf(v.x); o.y = f2bf(v.y); o.z = f2bf(v.z); o.w = f2bf(v.w);
    ((ushort4*)dst)[i] = o;
  }
}

// ---------------------------------------------------------------------------
// bf16 MFMA GEMM: C(M,N) = A(M,K) @ B(N,K)^T + bias(N)
// 128x128 tile, BK=32, 256 thr = 4 waves (2x2), each wave 64x64 out.
// ---------------------------------------------------------------------------
template<int LDC, bool OUT_BF16>
__global__ __launch_bounds__(256) void gemm_bf16_kernel(
    const unsigned short* __restrict__ A,
    const unsigned short* __restrict__ B,
    const float* __restrict__ bias,
    void* __restrict__ Cout, int K, int nbx)
{
  __shared__ unsigned short Abuf[128*32];
  __shared__ unsigned short Bbuf[128*32];

  const int nwg = gridDim.x;
  const int cpx = nwg >> 3;
  const int bid = blockIdx.x;
  const int swz = (bid & 7) * cpx + (bid >> 3);
  const int bx = swz % nbx;
  const int by = swz / nbx;

  const int tid  = threadIdx.x;
  const int lane = tid & 63;
  const int wid  = tid >> 6;
  const int wr   = wid >> 1;
  const int wc   = wid & 1;

  const int lr    = lane >> 2;
  const int lslot = lane & 3;

  f32x4 zero = {0.f, 0.f, 0.f, 0.f};
  f32x4 acc[4][4];
#pragma unroll
  for (int i = 0; i < 4; ++i)
#pragma unroll
    for (int j = 0; j < 4; ++j) acc[i][j] = zero;

  const size_t arow0 = (size_t)by * 128;
  const size_t brow0 = (size_t)bx * 128;

  for (int k0 = 0; k0 < K; k0 += 32) {
#pragma unroll
    for (int i = 0; i < 2; ++i) {
      const int Rb = wid*32 + i*16;
      const int r  = Rb + lr;
      const int c8 = lslot ^ ((r >> 1) & 3);
      const unsigned short* ga = A + (arow0 + r)*(size_t)K + k0 + c8*8;
      const unsigned short* gb = B + (brow0 + r)*(size_t)K + k0 + c8*8;
      __builtin_amdgcn_global_load_lds(
          (const __attribute__((address_space(1))) void*)ga,
          (__attribute__((address_space(3))) void*)(Abuf + Rb*32), 16, 0, 0);
      __builtin_amdgcn_global_load_lds(
          (const __attribute__((address_space(1))) void*)gb,
          (__attribute__((address_space(3))) void*)(Bbuf + Rb*32), 16, 0, 0);
    }
    __syncthreads();

    const int lrow = lane & 15, k8 = lane >> 4;
    bf16x8 af[4], bfr[4];
#pragma unroll
    for (int mi = 0; mi < 4; ++mi) {
      int r = wr*64 + mi*16 + lrow;
      af[mi] = *(const bf16x8*)&Abuf[r*32 + (k8 ^ ((r >> 1) & 3))*8];
    }
#pragma unroll
    for (int nj = 0; nj < 4; ++nj) {
      int r = wc*64 + nj*16 + lrow;
      bfr[nj] = *(const bf16x8*)&Bbuf[r*32 + (k8 ^ ((r >> 1) & 3))*8];
    }
#pragma unroll
    for (int mi = 0; mi < 4; ++mi)
#pragma unroll
      for (int nj = 0; nj < 4; ++nj)
        acc[mi][nj] = __builtin_amdgcn_mfma_f32_16x16x32_bf16(
                          af[mi], bfr[nj], acc[mi][nj], 0, 0, 0);
    __syncthreads();
  }

  const int lcol = lane & 15, lrq = lane >> 4;
#pragma unroll
  for (int nj = 0; nj < 4; ++nj) {
    const int colg = bx*128 + wc*64 + nj*16 + lcol;
    const float bv = bias[colg];
#pragma unroll
    for (int mi = 0; mi < 4; ++mi) {
      const int rowg = by*128 + wr*64 + mi*16 + lrq*4;
#pragma unroll
      for (int q = 0; q < 4; ++q) {
        float v = acc[mi][nj][q] + bv;
        if constexpr (OUT_BF16)
          ((unsigned short*)Cout)[(size_t)(rowg + q)*LDC + colg] = f2bf(v);
        else
          ((float*)Cout)[(size_t)(rowg + q)*LDC + colg] = v;
      }
    }
  }
}

// ---------------------------------------------------------------------------
// dbc = x @ W_x^T + b_x via MFMA.  x = ui_bf[:, 0:2048] (bf16, ld 4096),
// W_x bf16 (96 x 2048).  M-tile 64, N = 96 (6x16 frags), BK = 32.
// grid = MT/64 = 64 blocks, 256 threads = 4 waves; wave w: rows w*16..w*16+15.
// ---------------------------------------------------------------------------
__global__ __launch_bounds__(256) void dbc_mfma_kernel(
    const unsigned short* __restrict__ A,     // ui_bf
    const unsigned short* __restrict__ Bw,    // wx_bf
    const float* __restrict__ bx,
    float* __restrict__ dbc)
{
  __shared__ unsigned short Abuf[64*32];   // 4 KiB
  __shared__ unsigned short Bbuf[96*32];   // 6 KiB

  const int tid  = threadIdx.x;
  const int lane = tid & 63;
  const int wid  = tid >> 6;
  const int lr    = lane >> 2;
  const int lslot = lane & 3;
  const size_t arow0 = (size_t)blockIdx.x * 64;

  f32x4 zero = {0.f, 0.f, 0.f, 0.f};
  f32x4 acc[6];
#pragma unroll
  for (int j = 0; j < 6; ++j) acc[j] = zero;

  for (int k0 = 0; k0 < DI; k0 += 32) {
    {  // stage A: 64 rows, each wave one 16-row group
      const int Rb = wid*16;
      const int r  = Rb + lr;
      const int c8 = lslot ^ ((r >> 1) & 3);
      const unsigned short* ga = A + (arow0 + r)*4096 + k0 + c8*8;
      __builtin_amdgcn_global_load_lds(
          (const __attribute__((address_space(1))) void*)ga,
          (__attribute__((address_space(3))) void*)(Abuf + Rb*32), 16, 0, 0);
    }
    if (wid < 3) {  // stage B: 96 rows, waves 0..2 two groups each
#pragma unroll
      for (int i = 0; i < 2; ++i) {
        const int Rb = wid*32 + i*16;
        const int r  = Rb + lr;
        const int c8 = lslot ^ ((r >> 1) & 3);
        const unsigned short* gb = Bw + (size_t)r*DI + k0 + c8*8;
        __builtin_amdgcn_global_load_lds(
            (const __attribute__((address_space(1))) void*)gb,
            (__attribute__((address_space(3))) void*)(Bbuf + Rb*32), 16, 0, 0);
      }
    }
    __syncthreads();

    const int lrow = lane & 15, k8 = lane >> 4;
    const int ra = wid*16 + lrow;
    bf16x8 af = *(const bf16x8*)&Abuf[ra*32 + (k8 ^ ((ra >> 1) & 3))*8];
#pragma unroll
    for (int nj = 0; nj < 6; ++nj) {
      const int rb = nj*16 + lrow;
      bf16x8 bf_ = *(const bf16x8*)&Bbuf[rb*32 + (k8 ^ ((rb >> 1) & 3))*8];
      acc[nj] = __builtin_amdgcn_mfma_f32_16x16x32_bf16(af, bf_, acc[nj], 0, 0, 0);
    }
    __syncthreads();
  }

  const int lcol = lane & 15, lrq = lane >> 4;
  const int rowg = (int)arow0 + wid*16 + lrq*4;
#pragma unroll
  for (int nj = 0; nj < 6; ++nj) {
    const int colg = nj*16 + lcol;
    const float bv = bx[colg];
#pragma unroll
    for (int q = 0; q < 4; ++q)
      dbc[(size_t)(rowg + q)*96 + colg] = acc[nj][q] + bv;
  }
}

// ---------------------------------------------------------------------------
// delta(m,n) = softplus( dbc[m, 0:64] . W_dt[n] + b_dt[n] )
// ---------------------------------------------------------------------------
__global__ __launch_bounds__(256) void delta_kernel(
    const float* __restrict__ dbc, const float* __restrict__ Wdt,
    const float* __restrict__ bdt, float* __restrict__ delta)
{
  __shared__ float draw[16][64];
  const int n  = blockIdx.x * 256 + threadIdx.x;
  const int m0 = blockIdx.y * 16;
  {
    int t = threadIdx.x;
    int r = t >> 4, c4 = t & 15;
    *(float4*)&draw[r][c4*4] = *(const float4*)(dbc + (size_t)(m0+r)*96 + c4*4);
  }
  float w[64];
  const float* wp = Wdt + (size_t)n*64;
#pragma unroll
  for (int k4 = 0; k4 < 16; ++k4) {
    float4 wv = *(const float4*)(wp + k4*4);
    w[k4*4+0] = wv.x; w[k4*4+1] = wv.y; w[k4*4+2] = wv.z; w[k4*4+3] = wv.w;
  }
  __syncthreads();
  const float bb = bdt[n];
#pragma unroll 4
  for (int r = 0; r < 16; ++r) {
    float s = bb;
#pragma unroll
    for (int k = 0; k < 64; ++k) s += draw[r][k]*w[k];
    float sp = (s > 20.f) ? s : log1pf(expf(s));
    delta[(size_t)(m0+r)*DI + n] = sp;
  }
}

// ---------------------------------------------------------------------------
// Chunked scan, pass A: local scan from h=0; emits P = exp(A*sum dt), S = h_end
// ---------------------------------------------------------------------------
__global__ __launch_bounds__(256) void scanA_kernel(
    const unsigned short* __restrict__ uib,
    const float* __restrict__ dbc,
    const float* __restrict__ delta,
    const float* __restrict__ A_log,
    float* __restrict__ P,
    float* __restrict__ S)
{
  const int gid = blockIdx.x*256 + threadIdx.x;
  const int d   = gid & (DI-1);
  const int rem = gid >> 11;
  const int c   = rem & (CHK-1);
  const int b   = rem >> 5;

  float A[NST];
  {
    const float4* ap = (const float4*)(A_log + (size_t)d*NST);
#pragma unroll
    for (int q = 0; q < 4; ++q) {
      float4 v = ap[q];
      A[q*4+0] = -expf(v.x); A[q*4+1] = -expf(v.y);
      A[q*4+2] = -expf(v.z); A[q*4+3] = -expf(v.w);
    }
  }

  float h[NST];
#pragma unroll
  for (int nn = 0; nn < NST; ++nn) h[nn] = 0.f;
  float sdt = 0.f;

  const int t0 = c * LCH;
  const float* dptr          = delta + ((size_t)b*SEQ + t0)*DI + d;
  const unsigned short* xptr = uib   + ((size_t)b*SEQ + t0)*4096 + d;
  const float* bptr          = dbc   + ((size_t)b*SEQ + t0)*96 + 64;

  float dt = dptr[0];
  float xv = bf2f(xptr[0]);
  float4 Bv0 = *(const float4*)(bptr + 0);
  float4 Bv1 = *(const float4*)(bptr + 4);
  float4 Bv2 = *(const float4*)(bptr + 8);
  float4 Bv3 = *(const float4*)(bptr + 12);

  for (int t = 0; t < LCH; ++t) {
    const float dtc = dt, xvc = xv;
    float Bc[NST] = {Bv0.x,Bv0.y,Bv0.z,Bv0.w, Bv1.x,Bv1.y,Bv1.z,Bv1.w,
                     Bv2.x,Bv2.y,Bv2.z,Bv2.w, Bv3.x,Bv3.y,Bv3.z,Bv3.w};
    if (t + 1 < LCH) {
      const size_t tn = (size_t)(t+1);
      dt = dptr[tn*DI];
      xv = bf2f(xptr[tn*4096]);
      const float* bp = bptr + tn*96;
      Bv0 = *(const float4*)(bp + 0);
      Bv1 = *(const float4*)(bp + 4);
      Bv2 = *(const float4*)(bp + 8);
      Bv3 = *(const float4*)(bp + 12);
    }
    sdt += dtc;
    const float xdt = xvc * dtc;
#pragma unroll
    for (int nn = 0; nn < NST; ++nn) {
      float dA = __expf(dtc * A[nn]);
      h[nn] = h[nn]*dA + xdt*Bc[nn];
    }
  }

  float* Pp = P + (((size_t)b*CHK + c)*DI + d)*NST;
  float* Sp = S + (((size_t)b*CHK + c)*DI + d)*NST;
#pragma unroll
  for (int q = 0; q < 4; ++q) {
    float4 pv = { __expf(A[q*4+0]*sdt), __expf(A[q*4+1]*sdt),
                  __expf(A[q*4+2]*sdt), __expf(A[q*4+3]*sdt) };
    float4 sv = { h[q*4+0], h[q*4+1], h[q*4+2], h[q*4+3] };
    *(float4*)(Pp + q*4) = pv;
    *(float4*)(Sp + q*4) = sv;
  }
}

// ---------------------------------------------------------------------------
// Chunked scan, pass B: inter-chunk scan; S replaced by carry-in state.
// ---------------------------------------------------------------------------
__global__ __launch_bounds__(256) void scanB_kernel(
    const float* __restrict__ P, float* __restrict__ S)
{
  const int gid = blockIdx.x*256 + threadIdx.x;
  const int n4 = gid & 3;
  const int d  = (gid >> 2) & (DI-1);
  const int b  = gid >> 13;

  float4 h = {0.f, 0.f, 0.f, 0.f};
  for (int c = 0; c < CHK; ++c) {
    const size_t idx = (((size_t)b*CHK + c)*DI + d)*NST + n4*4;
    float4 p = *(const float4*)(P + idx);
    float4 s = *(const float4*)(S + idx);
    *(float4*)(S + idx) = h;
    h.x = h.x*p.x + s.x;
    h.y = h.y*p.y + s.y;
    h.z = h.z*p.z + s.z;
    h.w = h.w*p.w + s.w;
  }
}

// ---------------------------------------------------------------------------
// Chunked scan, pass C: seeded local scan; y + skip + SiLU gate -> y_bf (bf16)
// ---------------------------------------------------------------------------
__global__ __launch_bounds__(256) void scanC_kernel(
    const unsigned short* __restrict__ uib,
    const float* __restrict__ dbc,
    const float* __restrict__ delta,
    const float* __restrict__ A_log,
    const float* __restrict__ Dp,
    const float* __restrict__ S,
    unsigned short* __restrict__ y_bf)
{
  const int gid = blockIdx.x*256 + threadIdx.x;
  const int d   = gid & (DI-1);
  const int rem = gid >> 11;
  const int c   = rem & (CHK-1);
  const int b   = rem >> 5;

  float A[NST];
  {
    const float4* ap = (const float4*)(A_log + (size_t)d*NST);
#pragma unroll
    for (int q = 0; q < 4; ++q) {
      float4 v = ap[q];
      A[q*4+0] = -expf(v.x); A[q*4+1] = -expf(v.y);
      A[q*4+2] = -expf(v.z); A[q*4+3] = -expf(v.w);
    }
  }
  const float Dv = Dp[d];

  float h[NST];
  {
    const float* Sp = S + (((size_t)b*CHK + c)*DI + d)*NST;
#pragma unroll
    for (int q = 0; q < 4; ++q) {
      float4 sv = *(const float4*)(Sp + q*4);
      h[q*4+0] = sv.x; h[q*4+1] = sv.y; h[q*4+2] = sv.z; h[q*4+3] = sv.w;
    }
  }

  const int t0 = c * LCH;
  const float* dptr          = delta + ((size_t)b*SEQ + t0)*DI + d;
  const unsigned short* xptr = uib   + ((size_t)b*SEQ + t0)*4096 + d;
  const float* cptr          = dbc   + ((size_t)b*SEQ + t0)*96;
  unsigned short* yp         = y_bf  + ((size_t)b*SEQ + t0)*DI + d;

  float dt = dptr[0];
  float xv = bf2f(xptr[0]);
  float zv = bf2f(xptr[2048]);
  float4 Bv0 = *(const float4*)(cptr + 64);
  float4 Bv1 = *(const float4*)(cptr + 68);
  float4 Bv2 = *(const float4*)(cptr + 72);
  float4 Bv3 = *(const float4*)(cptr + 76);
  float4 Cv0 = *(const float4*)(cptr + 80);
  float4 Cv1 = *(const float4*)(cptr + 84);
  float4 Cv2 = *(const float4*)(cptr + 88);
  float4 Cv3 = *(const float4*)(cptr + 92);

  for (int t = 0; t < LCH; ++t) {
    const float dtc = dt, xvc = xv, zvc = zv;
    float Bc[NST] = {Bv0.x,Bv0.y,Bv0.z,Bv0.w, Bv1.x,Bv1.y,Bv1.z,Bv1.w,
                     Bv2.x,Bv2.y,Bv2.z,Bv2.w, Bv3.x,Bv3.y,Bv3.z,Bv3.w};
    float Cc[NST] = {Cv0.x,Cv0.y,Cv0.z,Cv0.w, Cv1.x,Cv1.y,Cv1.z,Cv1.w,
                     Cv2.x,Cv2.y,Cv2.z,Cv2.w, Cv3.x,Cv3.y,Cv3.z,Cv3.w};
    if (t + 1 < LCH) {
      const size_t tn = (size_t)(t+1);
      dt = dptr[tn*DI];
      xv = bf2f(xptr[tn*4096]);
      zv = bf2f(xptr[tn*4096 + 2048]);
      const float* cp = cptr + tn*96;
      Bv0 = *(const float4*)(cp + 64);
      Bv1 = *(const float4*)(cp + 68);
      Bv2 = *(const float4*)(cp + 72);
      Bv3 = *(const float4*)(cp + 76);
      Cv0 = *(const float4*)(cp + 80);
      Cv1 = *(const float4*)(cp + 84);
      Cv2 = *(const float4*)(cp + 88);
      Cv3 = *(const float4*)(cp + 92);
    }
    const float xdt = xvc * dtc;
    float y = 0.f;
#pragma unroll
    for (int nn = 0; nn < NST; ++nn) {
      float dA = __expf(dtc * A[nn]);
      h[nn] = h[nn]*dA + xdt*Bc[nn];
      y += h[nn]*Cc[nn];
    }
    y += xvc * Dv;
    y *= zvc / (1.f + __expf(-zvc));
    yp[(size_t)t*DI] = f2bf(y);
  }
}

// ---------------------------------------------------------------------------
extern "C" void kernel_launch(void* const* d_in, const int* in_sizes, int n_in,
                              void* d_out, int out_size, void* d_ws, size_t ws_size,
                              hipStream_t stream)
{
  const float* u     = (const float*)d_in[0];
  const float* W_in  = (const float*)d_in[1];
  const float* b_in  = (const float*)d_in[2];
  const float* W_x   = (const float*)d_in[3];
  const float* b_x   = (const float*)d_in[4];
  const float* W_dt  = (const float*)d_in[5];
  const float* b_dt  = (const float*)d_in[6];
  const float* A_log = (const float*)d_in[7];
  const float* Dp    = (const float*)d_in[8];
  const float* W_out = (const float*)d_in[9];
  const float* b_out = (const float*)d_in[10];
  float* out = (float*)d_out;

  // workspace (~90 MB total)
  unsigned short* ui_bf   = (unsigned short*)d_ws;            // MT*4096 bf16
  float*          dbc     = (float*)(ui_bf + (size_t)MT*4096);// MT*96 f32
  float*          delta   = dbc + (size_t)MT*96;              // MT*DI f32
  unsigned short* y_bf    = (unsigned short*)(delta + (size_t)MT*DI); // MT*DI bf16
  unsigned short* wout_bf = y_bf + (size_t)MT*DI;             // DM*DI bf16
  unsigned short* wx_bf   = wout_bf + (size_t)DM*DI;          // 96*DI bf16

  // d_out doubles as scratch: u_bf+Win_bf (before scanA), then P+S, then out
  unsigned short* u_bf   = (unsigned short*)d_out;            // MT*DM bf16
  unsigned short* win_bf = u_bf + (size_t)MT*DM;              // 2DI*DM bf16
  float* P = (float*)d_out;                                   // B*CHK*DI*NST
  float* S = P + (size_t)BATCH*CHK*DI*NST;

  // 0) fp32 -> bf16 conversions
  conv_bf16_kernel<<<4096, 256, 0, stream>>>(u,     u_bf,    MT*DM/4);
  conv_bf16_kernel<<<4096, 256, 0, stream>>>(W_in,  win_bf,  2*DI*DM/4);
  conv_bf16_kernel<<<2048, 256, 0, stream>>>(W_out, wout_bf, DM*DI/4);
  conv_bf16_kernel<<<192,  256, 0, stream>>>(W_x,   wx_bf,   96*DI/4);

  // 1) ui = u @ W_in^T + b_in   (M=4096, N=4096, K=1024) -> bf16
  gemm_bf16_kernel<4096, true><<<32*32, 256, 0, stream>>>(
      u_bf, win_bf, b_in, ui_bf, DM, 32);

  // 2) dbc = x @ W_x^T + b_x    (MFMA, N=96, K=2048)
  dbc_mfma_kernel<<<MT/64, 256, 0, stream>>>(ui_bf, wx_bf, b_x, dbc);

  // 3) delta = softplus(draw @ W_dt^T + b_dt)
  delta_kernel<<<dim3(DI/256, MT/16), 256, 0, stream>>>(dbc, W_dt, b_dt, delta);

  // 4) chunk-parallel selective scan (P,S overwrite u_bf/win_bf — dead now)
  scanA_kernel<<<BATCH*CHK*DI/256, 256, 0, stream>>>(ui_bf, dbc, delta, A_log, P, S);
  scanB_kernel<<<BATCH*DI*4/256, 256, 0, stream>>>(P, S);
  scanC_kernel<<<BATCH*CHK*DI/256, 256, 0, stream>>>(ui_bf, dbc, delta, A_log, Dp, S, y_bf);

  // 5) out = y @ W_out^T + b_out (M=4096, N=1024, K=2048) -> f32 (overwrites P,S)
  gemm_bf16_kernel<1024, false><<<8*32, 256, 0, stream>>>(
      y_bf, wout_bf, b_out, out, DI, 8);
}

// Round 5
// 265.913 us; speedup vs baseline: 7.0812x; 1.0693x over previous
//
#include <hip/hip_runtime.h>
#include <math.h>

#define BATCH 2
#define SEQ   2048
#define DM    1024
#define DI    2048
#define NST   16
#define MT    (BATCH*SEQ)   // 4096
#define CHK   32            // chunks along T
#define LCH   (SEQ/CHK)     // 64 steps per chunk

typedef __attribute__((ext_vector_type(8))) short  bf16x8;
typedef __attribute__((ext_vector_type(4))) float  f32x4;

static __device__ __forceinline__ unsigned short f2bf(float f) {
  unsigned u = __float_as_uint(f);
  u += 0x7fff + ((u >> 16) & 1);          // RNE
  return (unsigned short)(u >> 16);
}
static __device__ __forceinline__ float bf2f(unsigned short h) {
  return __uint_as_float(((unsigned)h) << 16);
}

// ---------------------------------------------------------------------------
// fp32 -> bf16 bulk convert (float4 in, ushort4 out)
// ---------------------------------------------------------------------------
__global__ __launch_bounds__(256) void conv_bf16_kernel(
    const float* __restrict__ src, unsigned short* __restrict__ dst, int n4)
{
  int i = blockIdx.x * 256 + threadIdx.x;
  if (i < n4) {
    float4 v = ((const float4*)src)[i];
    ushort4 o;
    o.x = f2bf(v.x); o.y = f2bf(v.y); o.z = f2bf(v.z); o.w = f2bf(v.w);
    ((ushort4*)dst)[i] = o;
  }
}

// ---------------------------------------------------------------------------
// bf16 MFMA GEMM v2: C(M,N) = A(M,K) @ B(N,K)^T + bias(N)
// Tile 128 x BN (BN = 128 or 64), BK = 64 (two proven BK=32 sub-tiles),
// 256 thr = 4 waves (2x2); wave tile 64 x BN/2.
// Double-buffered LDS; next K-tile staged via global_load_lds BEFORE the
// current tile's ds_read+MFMA, single __syncthreads (vmcnt drain) per K-tile.
// Swizzle: 16B-slot ^= (row>>1)&3, applied on global source + read side.
// ---------------------------------------------------------------------------
template<int BN, bool OUT_BF16, int LDC>
__global__ __launch_bounds__(256, 2) void gemm2_kernel(
    const unsigned short* __restrict__ A,
    const unsigned short* __restrict__ B,
    const float* __restrict__ bias,
    void* __restrict__ Cout, int K, int nbx)
{
  constexpr int NJ = BN / 32;               // N-frags per wave
  __shared__ unsigned short Abuf[2][2][128*32];   // [buf][k-half][row*32+col]
  __shared__ unsigned short Bbuf[2][2][BN*32];

  // XCD-aware block swizzle (grid % 8 == 0)
  const int nwg = gridDim.x;
  const int cpx = nwg >> 3;
  const int bid = blockIdx.x;
  const int swz = (bid & 7) * cpx + (bid >> 3);
  const int bx = swz % nbx;
  const int by = swz / nbx;

  const int tid  = threadIdx.x;
  const int lane = tid & 63;
  const int wid  = tid >> 6;
  const int wr   = wid >> 1;    // wave row (0..1)
  const int wc   = wid & 1;     // wave col (0..1)
  const int lr    = lane >> 2;  // staging: row within 16-row group
  const int lslot = lane & 3;   // staging: 16B slot within 32-elem row

  f32x4 zero = {0.f, 0.f, 0.f, 0.f};
  f32x4 acc[4][NJ];
#pragma unroll
  for (int i = 0; i < 4; ++i)
#pragma unroll
    for (int j = 0; j < NJ; ++j) acc[i][j] = zero;

  const size_t arow0 = (size_t)by * 128;
  const size_t brow0 = (size_t)bx * BN;
  const int NT = K >> 6;        // K-tiles of 64

  // --- staging: one K-tile (both 32-halves of A and B) into buffer `buf`
  auto STAGE = [&](int buf, int k0) {
#pragma unroll
    for (int half = 0; half < 2; ++half) {
#pragma unroll
      for (int i = 0; i < 2; ++i) {         // A: 8 groups of 16 rows
        const int Rb = (wid + i*4) * 16;
        const int r  = Rb + lr;
        const int c8 = lslot ^ ((r >> 1) & 3);
        const unsigned short* ga = A + (arow0 + r)*(size_t)K + k0 + half*32 + c8*8;
        __builtin_amdgcn_global_load_lds(
            (const __attribute__((address_space(1))) void*)ga,
            (__attribute__((address_space(3))) void*)(&Abuf[buf][half][Rb*32]),
            16, 0, 0);
      }
#pragma unroll
      for (int i = 0; i < BN/64; ++i) {     // B: BN/16 groups
        const int Rb = (wid + i*4) * 16;
        const int r  = Rb + lr;
        const int c8 = lslot ^ ((r >> 1) & 3);
        const unsigned short* gb = B + (brow0 + r)*(size_t)K + k0 + half*32 + c8*8;
        __builtin_amdgcn_global_load_lds(
            (const __attribute__((address_space(1))) void*)gb,
            (__attribute__((address_space(3))) void*)(&Bbuf[buf][half][Rb*32]),
            16, 0, 0);
      }
    }
  };

  STAGE(0, 0);
  __syncthreads();              // drain prologue stage

  const int lrow = lane & 15, k8 = lane >> 4;
  int cur = 0;
  for (int kt = 0; kt < NT; ++kt) {
    if (kt + 1 < NT) STAGE(cur ^ 1, (kt + 1) * 64);   // prefetch next tile

#pragma unroll
    for (int half = 0; half < 2; ++half) {
      bf16x8 af[4], bfr[NJ];
#pragma unroll
      for (int mi = 0; mi < 4; ++mi) {
        const int r = wr*64 + mi*16 + lrow;
        af[mi] = *(const bf16x8*)&Abuf[cur][half][r*32 + (k8 ^ ((r >> 1) & 3))*8];
      }
#pragma unroll
      for (int nj = 0; nj < NJ; ++nj) {
        const int r = wc*(BN/2) + nj*16 + lrow;
        bfr[nj] = *(const bf16x8*)&Bbuf[cur][half][r*32 + (k8 ^ ((r >> 1) & 3))*8];
      }
      __builtin_amdgcn_s_setprio(1);
#pragma unroll
      for (int mi = 0; mi < 4; ++mi)
#pragma unroll
        for (int nj = 0; nj < NJ; ++nj)
          acc[mi][nj] = __builtin_amdgcn_mfma_f32_16x16x32_bf16(
                            af[mi], bfr[nj], acc[mi][nj], 0, 0, 0);
      __builtin_amdgcn_s_setprio(0);
    }
    __syncthreads();            // vmcnt(0)+lgkm drain: next tile ready,
    cur ^= 1;                   // and protects buf we just read
  }

  // epilogue: C/D layout col=lane&15, row=(lane>>4)*4+q
  const int lcol = lane & 15, lrq = lane >> 4;
#pragma unroll
  for (int nj = 0; nj < NJ; ++nj) {
    const int colg = bx*BN + wc*(BN/2) + nj*16 + lcol;
    const float bv = bias[colg];
#pragma unroll
    for (int mi = 0; mi < 4; ++mi) {
      const int rowg = by*128 + wr*64 + mi*16 + lrq*4;
#pragma unroll
      for (int q = 0; q < 4; ++q) {
        float v = acc[mi][nj][q] + bv;
        if constexpr (OUT_BF16)
          ((unsigned short*)Cout)[(size_t)(rowg + q)*LDC + colg] = f2bf(v);
        else
          ((float*)Cout)[(size_t)(rowg + q)*LDC + colg] = v;
      }
    }
  }
}

// ---------------------------------------------------------------------------
// dbc = x @ W_x^T + b_x via MFMA.  x = ui_bf[:, 0:2048] (bf16, ld 4096),
// W_x bf16 (96 x 2048).  M-tile 64, N = 96 (6x16 frags), BK = 32.
// ---------------------------------------------------------------------------
__global__ __launch_bounds__(256) void dbc_mfma_kernel(
    const unsigned short* __restrict__ A,     // ui_bf
    const unsigned short* __restrict__ Bw,    // wx_bf
    const float* __restrict__ bx,
    float* __restrict__ dbc)
{
  __shared__ unsigned short Abuf[64*32];   // 4 KiB
  __shared__ unsigned short Bbuf[96*32];   // 6 KiB

  const int tid  = threadIdx.x;
  const int lane = tid & 63;
  const int wid  = tid >> 6;
  const int lr    = lane >> 2;
  const int lslot = lane & 3;
  const size_t arow0 = (size_t)blockIdx.x * 64;

  f32x4 zero = {0.f, 0.f, 0.f, 0.f};
  f32x4 acc[6];
#pragma unroll
  for (int j = 0; j < 6; ++j) acc[j] = zero;

  for (int k0 = 0; k0 < DI; k0 += 32) {
    {
      const int Rb = wid*16;
      const int r  = Rb + lr;
      const int c8 = lslot ^ ((r >> 1) & 3);
      const unsigned short* ga = A + (arow0 + r)*4096 + k0 + c8*8;
      __builtin_amdgcn_global_load_lds(
          (const __attribute__((address_space(1))) void*)ga,
          (__attribute__((address_space(3))) void*)(Abuf + Rb*32), 16, 0, 0);
    }
    if (wid < 3) {
#pragma unroll
      for (int i = 0; i < 2; ++i) {
        const int Rb = wid*32 + i*16;
        const int r  = Rb + lr;
        const int c8 = lslot ^ ((r >> 1) & 3);
        const unsigned short* gb = Bw + (size_t)r*DI + k0 + c8*8;
        __builtin_amdgcn_global_load_lds(
            (const __attribute__((address_space(1))) void*)gb,
            (__attribute__((address_space(3))) void*)(Bbuf + Rb*32), 16, 0, 0);
      }
    }
    __syncthreads();

    const int lrow = lane & 15, k8 = lane >> 4;
    const int ra = wid*16 + lrow;
    bf16x8 af = *(const bf16x8*)&Abuf[ra*32 + (k8 ^ ((ra >> 1) & 3))*8];
#pragma unroll
    for (int nj = 0; nj < 6; ++nj) {
      const int rb = nj*16 + lrow;
      bf16x8 bf_ = *(const bf16x8*)&Bbuf[rb*32 + (k8 ^ ((rb >> 1) & 3))*8];
      acc[nj] = __builtin_amdgcn_mfma_f32_16x16x32_bf16(af, bf_, acc[nj], 0, 0, 0);
    }
    __syncthreads();
  }

  const int lcol = lane & 15, lrq = lane >> 4;
  const int rowg = (int)arow0 + wid*16 + lrq*4;
#pragma unroll
  for (int nj = 0; nj < 6; ++nj) {
    const int colg = nj*16 + lcol;
    const float bv = bx[colg];
#pragma unroll
    for (int q = 0; q < 4; ++q)
      dbc[(size_t)(rowg + q)*96 + colg] = acc[nj][q] + bv;
  }
}

// ---------------------------------------------------------------------------
// delta(m,n) = softplus( dbc[m, 0:64] . W_dt[n] + b_dt[n] )
// ---------------------------------------------------------------------------
__global__ __launch_bounds__(256) void delta_kernel(
    const float* __restrict__ dbc, const float* __restrict__ Wdt,
    const float* __restrict__ bdt, float* __restrict__ delta)
{
  __shared__ float draw[16][64];
  const int n  = blockIdx.x * 256 + threadIdx.x;
  const int m0 = blockIdx.y * 16;
  {
    int t = threadIdx.x;
    int r = t >> 4, c4 = t & 15;
    *(float4*)&draw[r][c4*4] = *(const float4*)(dbc + (size_t)(m0+r)*96 + c4*4);
  }
  float w[64];
  const float* wp = Wdt + (size_t)n*64;
#pragma unroll
  for (int k4 = 0; k4 < 16; ++k4) {
    float4 wv = *(const float4*)(wp + k4*4);
    w[k4*4+0] = wv.x; w[k4*4+1] = wv.y; w[k4*4+2] = wv.z; w[k4*4+3] = wv.w;
  }
  __syncthreads();
  const float bb = bdt[n];
#pragma unroll 4
  for (int r = 0; r < 16; ++r) {
    float s = bb;
#pragma unroll
    for (int k = 0; k < 64; ++k) s += draw[r][k]*w[k];
    float sp = (s > 20.f) ? s : log1pf(expf(s));
    delta[(size_t)(m0+r)*DI + n] = sp;
  }
}

// ---------------------------------------------------------------------------
// Chunked scan, pass A: local scan from h=0; emits P = exp(A*sum dt), S = h_end
// ---------------------------------------------------------------------------
__global__ __launch_bounds__(256) void scanA_kernel(
    const unsigned short* __restrict__ uib,
    const float* __restrict__ dbc,
    const float* __restrict__ delta,
    const float* __restrict__ A_log,
    float* __restrict__ P,
    float* __restrict__ S)
{
  const int gid = blockIdx.x*256 + threadIdx.x;
  const int d   = gid & (DI-1);
  const int rem = gid >> 11;
  const int c   = rem & (CHK-1);
  const int b   = rem >> 5;

  float A[NST];
  {
    const float4* ap = (const float4*)(A_log + (size_t)d*NST);
#pragma unroll
    for (int q = 0; q < 4; ++q) {
      float4 v = ap[q];
      A[q*4+0] = -expf(v.x); A[q*4+1] = -expf(v.y);
      A[q*4+2] = -expf(v.z); A[q*4+3] = -expf(v.w);
    }
  }

  float h[NST];
#pragma unroll
  for (int nn = 0; nn < NST; ++nn) h[nn] = 0.f;
  float sdt = 0.f;

  const int t0 = c * LCH;
  const float* dptr          = delta + ((size_t)b*SEQ + t0)*DI + d;
  const unsigned short* xptr = uib   + ((size_t)b*SEQ + t0)*4096 + d;
  const float* bptr          = dbc   + ((size_t)b*SEQ + t0)*96 + 64;

  float dt = dptr[0];
  float xv = bf2f(xptr[0]);
  float4 Bv0 = *(const float4*)(bptr + 0);
  float4 Bv1 = *(const float4*)(bptr + 4);
  float4 Bv2 = *(const float4*)(bptr + 8);
  float4 Bv3 = *(const float4*)(bptr + 12);

  for (int t = 0; t < LCH; ++t) {
    const float dtc = dt, xvc = xv;
    float Bc[NST] = {Bv0.x,Bv0.y,Bv0.z,Bv0.w, Bv1.x,Bv1.y,Bv1.z,Bv1.w,
                     Bv2.x,Bv2.y,Bv2.z,Bv2.w, Bv3.x,Bv3.y,Bv3.z,Bv3.w};
    if (t + 1 < LCH) {
      const size_t tn = (size_t)(t+1);
      dt = dptr[tn*DI];
      xv = bf2f(xptr[tn*4096]);
      const float* bp = bptr + tn*96;
      Bv0 = *(const float4*)(bp + 0);
      Bv1 = *(const float4*)(bp + 4);
      Bv2 = *(const float4*)(bp + 8);
      Bv3 = *(const float4*)(bp + 12);
    }
    sdt += dtc;
    const float xdt = xvc * dtc;
#pragma unroll
    for (int nn = 0; nn < NST; ++nn) {
      float dA = __expf(dtc * A[nn]);
      h[nn] = h[nn]*dA + xdt*Bc[nn];
    }
  }

  float* Pp = P + (((size_t)b*CHK + c)*DI + d)*NST;
  float* Sp = S + (((size_t)b*CHK + c)*DI + d)*NST;
#pragma unroll
  for (int q = 0; q < 4; ++q) {
    float4 pv = { __expf(A[q*4+0]*sdt), __expf(A[q*4+1]*sdt),
                  __expf(A[q*4+2]*sdt), __expf(A[q*4+3]*sdt) };
    float4 sv = { h[q*4+0], h[q*4+1], h[q*4+2], h[q*4+3] };
    *(float4*)(Pp + q*4) = pv;
    *(float4*)(Sp + q*4) = sv;
  }
}

// ---------------------------------------------------------------------------
// Chunked scan, pass B: inter-chunk scan; S replaced by carry-in state.
// ---------------------------------------------------------------------------
__global__ __launch_bounds__(256) void scanB_kernel(
    const float* __restrict__ P, float* __restrict__ S)
{
  const int gid = blockIdx.x*256 + threadIdx.x;
  const int n4 = gid & 3;
  const int d  = (gid >> 2) & (DI-1);
  const int b  = gid >> 13;

  float4 h = {0.f, 0.f, 0.f, 0.f};
  for (int c = 0; c < CHK; ++c) {
    const size_t idx = (((size_t)b*CHK + c)*DI + d)*NST + n4*4;
    float4 p = *(const float4*)(P + idx);
    float4 s = *(const float4*)(S + idx);
    *(float4*)(S + idx) = h;
    h.x = h.x*p.x + s.x;
    h.y = h.y*p.y + s.y;
    h.z = h.z*p.z + s.z;
    h.w = h.w*p.w + s.w;
  }
}

// ---------------------------------------------------------------------------
// Chunked scan, pass C: seeded local scan; y + skip + SiLU gate -> y_bf (bf16)
// ---------------------------------------------------------------------------
__global__ __launch_bounds__(256) void scanC_kernel(
    const unsigned short* __restrict__ uib,
    const float* __restrict__ dbc,
    const float* __restrict__ delta,
    const float* __restrict__ A_log,
    const float* __restrict__ Dp,
    const float* __restrict__ S,
    unsigned short* __restrict__ y_bf)
{
  const int gid = blockIdx.x*256 + threadIdx.x;
  const int d   = gid & (DI-1);
  const int rem = gid >> 11;
  const int c   = rem & (CHK-1);
  const int b   = rem >> 5;

  float A[NST];
  {
    const float4* ap = (const float4*)(A_log + (size_t)d*NST);
#pragma unroll
    for (int q = 0; q < 4; ++q) {
      float4 v = ap[q];
      A[q*4+0] = -expf(v.x); A[q*4+1] = -expf(v.y);
      A[q*4+2] = -expf(v.z); A[q*4+3] = -expf(v.w);
    }
  }
  const float Dv = Dp[d];

  float h[NST];
  {
    const float* Sp = S + (((size_t)b*CHK + c)*DI + d)*NST;
#pragma unroll
    for (int q = 0; q < 4; ++q) {
      float4 sv = *(const float4*)(Sp + q*4);
      h[q*4+0] = sv.x; h[q*4+1] = sv.y; h[q*4+2] = sv.z; h[q*4+3] = sv.w;
    }
  }

  const int t0 = c * LCH;
  const float* dptr          = delta + ((size_t)b*SEQ + t0)*DI + d;
  const unsigned short* xptr = uib   + ((size_t)b*SEQ + t0)*4096 + d;
  const float* cptr          = dbc   + ((size_t)b*SEQ + t0)*96;
  unsigned short* yp         = y_bf  + ((size_t)b*SEQ + t0)*DI + d;

  float dt = dptr[0];
  float xv = bf2f(xptr[0]);
  float zv = bf2f(xptr[2048]);
  float4 Bv0 = *(const float4*)(cptr + 64);
  float4 Bv1 = *(const float4*)(cptr + 68);
  float4 Bv2 = *(const float4*)(cptr + 72);
  float4 Bv3 = *(const float4*)(cptr + 76);
  float4 Cv0 = *(const float4*)(cptr + 80);
  float4 Cv1 = *(const float4*)(cptr + 84);
  float4 Cv2 = *(const float4*)(cptr + 88);
  float4 Cv3 = *(const float4*)(cptr + 92);

  for (int t = 0; t < LCH; ++t) {
    const float dtc = dt, xvc = xv, zvc = zv;
    float Bc[NST] = {Bv0.x,Bv0.y,Bv0.z,Bv0.w, Bv1.x,Bv1.y,Bv1.z,Bv1.w,
                     Bv2.x,Bv2.y,Bv2.z,Bv2.w, Bv3.x,Bv3.y,Bv3.z,Bv3.w};
    float Cc[NST] = {Cv0.x,Cv0.y,Cv0.z,Cv0.w, Cv1.x,Cv1.y,Cv1.z,Cv1.w,
                     Cv2.x,Cv2.y,Cv2.z,Cv2.w, Cv3.x,Cv3.y,Cv3.z,Cv3.w};
    if (t + 1 < LCH) {
      const size_t tn = (size_t)(t+1);
      dt = dptr[tn*DI];
      xv = bf2f(xptr[tn*4096]);
      zv = bf2f(xptr[tn*4096 + 2048]);
      const float* cp = cptr + tn*96;
      Bv0 = *(const float4*)(cp + 64);
      Bv1 = *(const float4*)(cp + 68);
      Bv2 = *(const float4*)(cp + 72);
      Bv3 = *(const float4*)(cp + 76);
      Cv0 = *(const float4*)(cp + 80);
      Cv1 = *(const float4*)(cp + 84);
      Cv2 = *(const float4*)(cp + 88);
      Cv3 = *(const float4*)(cp + 92);
    }
    const float xdt = xvc * dtc;
    float y = 0.f;
#pragma unroll
    for (int nn = 0; nn < NST; ++nn) {
      float dA = __expf(dtc * A[nn]);
      h[nn] = h[nn]*dA + xdt*Bc[nn];
      y += h[nn]*Cc[nn];
    }
    y += xvc * Dv;
    y *= zvc / (1.f + __expf(-zvc));
    yp[(size_t)t*DI] = f2bf(y);
  }
}

// ---------------------------------------------------------------------------
extern "C" void kernel_launch(void* const* d_in, const int* in_sizes, int n_in,
                              void* d_out, int out_size, void* d_ws, size_t ws_size,
                              hipStream_t stream)
{
  const float* u     = (const float*)d_in[0];
  const float* W_in  = (const float*)d_in[1];
  const float* b_in  = (const float*)d_in[2];
  const float* W_x   = (const float*)d_in[3];
  const float* b_x   = (const float*)d_in[4];
  const float* W_dt  = (const float*)d_in[5];
  const float* b_dt  = (const float*)d_in[6];
  const float* A_log = (const float*)d_in[7];
  const float* Dp    = (const float*)d_in[8];
  const float* W_out = (const float*)d_in[9];
  const float* b_out = (const float*)d_in[10];
  float* out = (float*)d_out;

  // workspace (~90 MB total)
  unsigned short* ui_bf   = (unsigned short*)d_ws;            // MT*4096 bf16
  float*          dbc     = (float*)(ui_bf + (size_t)MT*4096);// MT*96 f32
  float*          delta   = dbc + (size_t)MT*96;              // MT*DI f32
  unsigned short* y_bf    = (unsigned short*)(delta + (size_t)MT*DI); // MT*DI bf16
  unsigned short* wout_bf = y_bf + (size_t)MT*DI;             // DM*DI bf16
  unsigned short* wx_bf   = wout_bf + (size_t)DM*DI;          // 96*DI bf16

  // d_out doubles as scratch: u_bf+Win_bf (before scanA), then P+S, then out
  unsigned short* u_bf   = (unsigned short*)d_out;            // MT*DM bf16
  unsigned short* win_bf = u_bf + (size_t)MT*DM;              // 2DI*DM bf16
  float* P = (float*)d_out;                                   // B*CHK*DI*NST
  float* S = P + (size_t)BATCH*CHK*DI*NST;

  // 0) fp32 -> bf16 conversions
  conv_bf16_kernel<<<4096, 256, 0, stream>>>(u,     u_bf,    MT*DM/4);
  conv_bf16_kernel<<<4096, 256, 0, stream>>>(W_in,  win_bf,  2*DI*DM/4);
  conv_bf16_kernel<<<2048, 256, 0, stream>>>(W_out, wout_bf, DM*DI/4);
  conv_bf16_kernel<<<192,  256, 0, stream>>>(W_x,   wx_bf,   96*DI/4);

  // 1) ui = u @ W_in^T + b_in   (M=4096, N=4096, K=1024) -> bf16
  gemm2_kernel<128, true, 4096><<<32*32, 256, 0, stream>>>(
      u_bf, win_bf, b_in, ui_bf, DM, 32);

  // 2) dbc = x @ W_x^T + b_x    (MFMA, N=96, K=2048)
  dbc_mfma_kernel<<<MT/64, 256, 0, stream>>>(ui_bf, wx_bf, b_x, dbc);

  // 3) delta = softplus(draw @ W_dt^T + b_dt)
  delta_kernel<<<dim3(DI/256, MT/16), 256, 0, stream>>>(dbc, W_dt, b_dt, delta);

  // 4) chunk-parallel selective scan (P,S overwrite u_bf/win_bf — dead now)
  scanA_kernel<<<BATCH*CHK*DI/256, 256, 0, stream>>>(ui_bf, dbc, delta, A_log, P, S);
  scanB_kernel<<<BATCH*DI*4/256, 256, 0, stream>>>(P, S);
  scanC_kernel<<<BATCH*CHK*DI/256, 256, 0, stream>>>(ui_bf, dbc, delta, A_log, Dp, S, y_bf);

  // 5) out = y @ W_out^T + b_out (M=4096, N=1024, K=2048) -> f32, BN=64
  gemm2_kernel<64, false, 1024><<<16*32, 256, 0, stream>>>(
      y_bf, wout_bf, b_out, out, DI, 16);
}